// Round 1
// baseline (776.233 us; speedup 1.0000x reference)
//
#include <hip/hip_runtime.h>
#include <hip/hip_bf16.h>

#define N_NODES 40000
#define N_EDGES 640000
#define E_TOT   (N_EDGES + N_NODES)
#define NUM_GRAPHS 64

// ---------------- CSR build ----------------

__global__ __launch_bounds__(256) void hist_kernel(const int* __restrict__ edst,
                                                   int* __restrict__ counts) {
    int e = blockIdx.x * 256 + threadIdx.x;
    if (e >= E_TOT) return;
    int d = (e < N_EDGES) ? edst[e] : (e - N_EDGES);
    atomicAdd(&counts[d], 1);
}

__global__ __launch_bounds__(1024) void scan_kernel(const int* __restrict__ counts,
                                                    int* __restrict__ offs) {
    __shared__ int part[1024];
    const int CH = 40;  // 1024*40 = 40960 >= 40000
    int tid = threadIdx.x;
    int base = tid * CH;
    int s = 0;
    for (int i = 0; i < CH; ++i) {
        int idx = base + i;
        if (idx < N_NODES) s += counts[idx];
    }
    part[tid] = s;
    __syncthreads();
    for (int off = 1; off < 1024; off <<= 1) {
        int t = (tid >= off) ? part[tid - off] : 0;
        __syncthreads();
        part[tid] += t;
        __syncthreads();
    }
    int run = part[tid] - s;  // exclusive prefix of this chunk
    for (int i = 0; i < CH; ++i) {
        int idx = base + i;
        if (idx < N_NODES) { offs[idx] = run; run += counts[idx]; }
    }
    if (tid == 1023) offs[N_NODES] = part[1023];
}

__global__ __launch_bounds__(256) void scatter_kernel(const int* __restrict__ esrc,
                                                      const int* __restrict__ edst,
                                                      const int* __restrict__ offs,
                                                      int* __restrict__ pos,
                                                      int* __restrict__ ssrc) {
    int e = blockIdx.x * 256 + threadIdx.x;
    if (e >= E_TOT) return;
    int d, s;
    if (e < N_EDGES) { d = edst[e]; s = esrc[e]; }
    else             { d = e - N_EDGES; s = d; }
    int idx = offs[d] + atomicAdd(&pos[d], 1);
    ssrc[idx] = s;
}

// ---------------- GEMM + attention scores ----------------
// h = X @ W   (K=128, M=128), als/ald fused. One wave -> 8 rows, lane -> 2 cols.
__global__ __launch_bounds__(256) void gemm128_attn(const float* __restrict__ X,
                                                    const float* __restrict__ W,
                                                    const float* __restrict__ asrc,
                                                    const float* __restrict__ adst,
                                                    float* __restrict__ H,
                                                    float* __restrict__ ALS,
                                                    float* __restrict__ ALD) {
    int wave = threadIdx.x >> 6;
    int lane = threadIdx.x & 63;
    int r0 = (blockIdx.x * 4 + wave) * 8;
    r0 = __builtin_amdgcn_readfirstlane(r0);
    if (r0 >= N_NODES) return;
    int c = lane * 2;
    int head = lane >> 4;
    float acc[8][2];
#pragma unroll
    for (int i = 0; i < 8; ++i) { acc[i][0] = 0.f; acc[i][1] = 0.f; }
    const float* x0 = X + (long)r0 * 128;
    for (int k = 0; k < 128; ++k) {
        float2 w2 = *(const float2*)(W + k * 128 + c);
#pragma unroll
        for (int i = 0; i < 8; ++i) {
            float xv = x0[i * 128 + k];
            acc[i][0] += xv * w2.x;
            acc[i][1] += xv * w2.y;
        }
    }
    float as0 = asrc[c], as1 = asrc[c + 1];
    float ad0 = adst[c], ad1 = adst[c + 1];
#pragma unroll
    for (int i = 0; i < 8; ++i) {
        int r = r0 + i;
        float h0 = acc[i][0], h1 = acc[i][1];
        *(float2*)(H + (long)r * 128 + c) = make_float2(h0, h1);
        float ps = h0 * as0 + h1 * as1;
        float pd = h0 * ad0 + h1 * ad1;
#pragma unroll
        for (int off = 8; off >= 1; off >>= 1) {
            ps += __shfl_xor(ps, off, 64);
            pd += __shfl_xor(pd, off, 64);
        }
        if ((lane & 15) == 0) {
            ALS[r * 4 + head] = ps;
            ALD[r * 4 + head] = pd;
        }
    }
}

// h2 = X @ W2  (K=128, M=32, 1 head). One wave -> 16 rows (2 half-waves x 8).
__global__ __launch_bounds__(256) void gemm32_attn(const float* __restrict__ X,
                                                   const float* __restrict__ W,
                                                   const float* __restrict__ asrc,
                                                   const float* __restrict__ adst,
                                                   float* __restrict__ H2,
                                                   float* __restrict__ ALS,
                                                   float* __restrict__ ALD) {
    int wave = threadIdx.x >> 6;
    int lane = threadIdx.x & 63;
    int col = lane & 31;
    int half = lane >> 5;
    int r0 = (blockIdx.x * 4 + wave) * 16;
    r0 = __builtin_amdgcn_readfirstlane(r0);
    if (r0 >= N_NODES) return;
    float acc[8];
#pragma unroll
    for (int i = 0; i < 8; ++i) acc[i] = 0.f;
    const float* x0 = X + (long)r0 * 128;
    for (int k = 0; k < 128; ++k) {
        float wv = W[k * 32 + col];
#pragma unroll
        for (int i = 0; i < 8; ++i) {
            float xv = x0[(i * 2 + half) * 128 + k];
            acc[i] += xv * wv;
        }
    }
    float as = asrc[col], ad = adst[col];
#pragma unroll
    for (int i = 0; i < 8; ++i) {
        int r = r0 + i * 2 + half;
        H2[r * 32 + col] = acc[i];
        float ps = acc[i] * as, pd = acc[i] * ad;
#pragma unroll
        for (int off = 16; off >= 1; off >>= 1) {
            ps += __shfl_xor(ps, off, 64);
            pd += __shfl_xor(pd, off, 64);
        }
        if (col == 0) { ALS[r] = ps; ALD[r] = pd; }
    }
}

// ---------------- Edge aggregation (softmax + weighted sum), CSR by dst ----------------
// One wave per node; lane -> 2 channels; head = lane>>4. Output gets +bias then ELU.
__global__ __launch_bounds__(256) void agg128(const float* __restrict__ H,
                                              const float* __restrict__ ALS,
                                              const float* __restrict__ ALD,
                                              const int* __restrict__ offs,
                                              const int* __restrict__ ssrc,
                                              const float* __restrict__ bias,
                                              float* __restrict__ OUT) {
    int n = blockIdx.x * 4 + (threadIdx.x >> 6);
    n = __builtin_amdgcn_readfirstlane(n);
    if (n >= N_NODES) return;
    int lane = threadIdx.x & 63;
    int c = lane * 2;
    int head = lane >> 4;
    float aldh = ALD[n * 4 + head];
    int j0 = __builtin_amdgcn_readfirstlane(offs[n]);
    int j1 = __builtin_amdgcn_readfirstlane(offs[n + 1]);
    float a0 = 0.f, a1 = 0.f, dsum = 0.f;
    for (int j = j0; j < j1; ++j) {
        int s = __builtin_amdgcn_readfirstlane(ssrc[j]);
        float e = ALS[s * 4 + head] + aldh;
        e = (e > 0.f) ? e : 0.2f * e;
        float w = __expf(e);
        dsum += w;
        float2 hv = *(const float2*)(H + (long)s * 128 + c);
        a0 += w * hv.x;
        a1 += w * hv.y;
    }
    float inv = 1.0f / dsum;
    float o0 = a0 * inv + bias[c];
    float o1 = a1 * inv + bias[c + 1];
    o0 = (o0 > 0.f) ? o0 : (__expf(o0) - 1.f);
    o1 = (o1 > 0.f) ? o1 : (__expf(o1) - 1.f);
    *(float2*)(OUT + (long)n * 128 + c) = make_float2(o0, o1);
}

// 32-channel, 1-head version; one wave handles 2 nodes (half-wave each).
__global__ __launch_bounds__(256) void agg32(const float* __restrict__ H2,
                                             const float* __restrict__ ALS,
                                             const float* __restrict__ ALD,
                                             const int* __restrict__ offs,
                                             const int* __restrict__ ssrc,
                                             const float* __restrict__ bias,
                                             float* __restrict__ OUT) {
    int wv = blockIdx.x * 4 + (threadIdx.x >> 6);
    int lane = threadIdx.x & 63;
    int col = lane & 31;
    int half = lane >> 5;
    int n = wv * 2 + half;
    if (n >= N_NODES) return;
    float aldn = ALD[n];
    int j0 = offs[n], j1 = offs[n + 1];
    float acc = 0.f, dsum = 0.f;
    for (int j = j0; j < j1; ++j) {
        int s = ssrc[j];
        float e = ALS[s] + aldn;
        e = (e > 0.f) ? e : 0.2f * e;
        float w = __expf(e);
        dsum += w;
        acc += w * H2[s * 32 + col];
    }
    float o = acc / dsum + bias[col];
    o = (o > 0.f) ? o : (__expf(o) - 1.f);
    OUT[n * 32 + col] = o;
}

// ---------------- Pooling + MLP ----------------

__global__ __launch_bounds__(256) void pool_kernel(const float* __restrict__ H3,
                                                   const int* __restrict__ batch,
                                                   float* __restrict__ gsum,
                                                   float* __restrict__ gcnt) {
    int idx = blockIdx.x * 256 + threadIdx.x;
    int n = idx >> 5, c = idx & 31;
    if (n >= N_NODES) return;
    int b = batch[n];
    atomicAdd(&gsum[b * 32 + c], H3[n * 32 + c]);
    if (c == 0) atomicAdd(&gcnt[b], 1.0f);
}

__global__ __launch_bounds__(256) void mlp_kernel(const float* __restrict__ gsum,
                                                  const float* __restrict__ gcnt,
                                                  const float* __restrict__ l1w,
                                                  const float* __restrict__ l1b,
                                                  const float* __restrict__ l2w,
                                                  const float* __restrict__ l2b,
                                                  float* __restrict__ out) {
    __shared__ float g[NUM_GRAPHS * 32];
    __shared__ float t1[NUM_GRAPHS * 128];
    int tid = threadIdx.x;
    for (int i = tid; i < NUM_GRAPHS * 32; i += 256) {
        float c = gcnt[i >> 5];
        g[i] = gsum[i] / fmaxf(c, 1.0f);
    }
    __syncthreads();
    for (int i = tid; i < NUM_GRAPHS * 128; i += 256) {
        int r = i >> 7, j = i & 127;
        float a = l1b[j];
        for (int k = 0; k < 32; ++k) a += g[r * 32 + k] * l1w[k * 128 + j];
        t1[i] = fmaxf(a, 0.f);
    }
    __syncthreads();
    for (int i = tid; i < NUM_GRAPHS * 8; i += 256) {
        int r = i >> 3, j = i & 7;
        float a = l2b[j];
        for (int k = 0; k < 128; ++k) a += t1[r * 128 + k] * l2w[k * 8 + j];
        out[i] = a;
    }
}

// ---------------- host ----------------

extern "C" void kernel_launch(void* const* d_in, const int* in_sizes, int n_in,
                              void* d_out, int out_size, void* d_ws, size_t ws_size,
                              hipStream_t stream) {
    const float* x      = (const float*)d_in[0];
    const int*   eidx   = (const int*)d_in[1];
    const int*   batch  = (const int*)d_in[2];
    const float* W0     = (const float*)d_in[3];
    const float* asrc0  = (const float*)d_in[4];
    const float* adst0  = (const float*)d_in[5];
    const float* b0     = (const float*)d_in[6];
    const float* W1     = (const float*)d_in[7];
    const float* asrc1  = (const float*)d_in[8];
    const float* adst1  = (const float*)d_in[9];
    const float* b1     = (const float*)d_in[10];
    const float* W2     = (const float*)d_in[11];
    const float* asrc2  = (const float*)d_in[12];
    const float* adst2  = (const float*)d_in[13];
    const float* b2     = (const float*)d_in[14];
    const float* l1w    = (const float*)d_in[15];
    const float* l1b    = (const float*)d_in[16];
    const float* l2w    = (const float*)d_in[17];
    const float* l2b    = (const float*)d_in[18];
    float* out = (float*)d_out;

    const int* esrc = eidx;
    const int* edst = eidx + N_EDGES;

    // workspace layout
    float* bufA = (float*)d_ws;                       // N*128
    float* bufB = bufA + (long)N_NODES * 128;         // N*128
    float* ALS  = bufB + (long)N_NODES * 128;         // N*4
    float* ALD  = ALS + N_NODES * 4;                  // N*4
    int* counts = (int*)(ALD + N_NODES * 4);          // N
    int* pos    = counts + N_NODES;                   // N
    float* gsum = (float*)(pos + N_NODES);            // 64*32
    float* gcnt = gsum + NUM_GRAPHS * 32;             // 64
    int* offs   = (int*)(gcnt + NUM_GRAPHS);          // N+1
    int* ssrc   = offs + (N_NODES + 1);               // E_TOT
    // reuse bufA for the 32-ch stage (bufA free after agg1 consumed it)
    float* h2a = bufA;                                // N*32
    float* h2b = bufA + (long)N_NODES * 32;           // N*32

    // zero counts, pos, gsum, gcnt (contiguous region)
    size_t zero_bytes = (size_t)(2 * N_NODES) * 4 + (NUM_GRAPHS * 32 + NUM_GRAPHS) * 4;
    hipMemsetAsync(counts, 0, zero_bytes, stream);

    int eblocks = (E_TOT + 255) / 256;
    hist_kernel<<<eblocks, 256, 0, stream>>>(edst, counts);
    scan_kernel<<<1, 1024, 0, stream>>>(counts, offs);
    scatter_kernel<<<eblocks, 256, 0, stream>>>(esrc, edst, offs, pos, ssrc);

    // layer 0: x[40000,128] @ W0 -> bufA, agg -> bufB (+b0, ELU)
    gemm128_attn<<<1250, 256, 0, stream>>>(x, W0, asrc0, adst0, bufA, ALS, ALD);
    agg128<<<10000, 256, 0, stream>>>(bufA, ALS, ALD, offs, ssrc, b0, bufB);

    // layer 1: bufB @ W1 -> bufA, agg -> bufB (+b1, ELU)
    gemm128_attn<<<1250, 256, 0, stream>>>(bufB, W1, asrc1, adst1, bufA, ALS, ALD);
    agg128<<<10000, 256, 0, stream>>>(bufA, ALS, ALD, offs, ssrc, b1, bufB);

    // layer 2: bufB @ W2 -> h2a (N,32), agg -> h2b (+b2, ELU)
    gemm32_attn<<<625, 256, 0, stream>>>(bufB, W2, asrc2, adst2, h2a, ALS, ALD);
    agg32<<<5000, 256, 0, stream>>>(h2a, ALS, ALD, offs, ssrc, b2, h2b);

    // pool + MLP
    pool_kernel<<<5000, 256, 0, stream>>>(h2b, batch, gsum, gcnt);
    mlp_kernel<<<1, 256, 0, stream>>>(gsum, gcnt, l1w, l1b, l2w, l2b, out);
}

// Round 2
// 506.016 us; speedup vs baseline: 1.5340x; 1.5340x over previous
//
#include <hip/hip_runtime.h>
#include <hip/hip_bf16.h>

#define N_NODES 40000
#define N_EDGES 640000
#define E_TOT   (N_EDGES + N_NODES)
#define NUM_GRAPHS 64

// ---------------- CSR build ----------------

__global__ __launch_bounds__(256) void hist_kernel(const int* __restrict__ edst,
                                                   int* __restrict__ counts) {
    int e = blockIdx.x * 256 + threadIdx.x;
    if (e >= E_TOT) return;
    int d = (e < N_EDGES) ? edst[e] : (e - N_EDGES);
    atomicAdd(&counts[d], 1);
}

__global__ __launch_bounds__(1024) void scan_kernel(const int* __restrict__ counts,
                                                    int* __restrict__ offs) {
    __shared__ int part[1024];
    const int CH = 40;  // 1024*40 = 40960 >= 40000
    int tid = threadIdx.x;
    int base = tid * CH;
    int s = 0;
    for (int i = 0; i < CH; ++i) {
        int idx = base + i;
        if (idx < N_NODES) s += counts[idx];
    }
    part[tid] = s;
    __syncthreads();
    for (int off = 1; off < 1024; off <<= 1) {
        int t = (tid >= off) ? part[tid - off] : 0;
        __syncthreads();
        part[tid] += t;
        __syncthreads();
    }
    int run = part[tid] - s;  // exclusive prefix of this chunk
    for (int i = 0; i < CH; ++i) {
        int idx = base + i;
        if (idx < N_NODES) { offs[idx] = run; run += counts[idx]; }
    }
    if (tid == 1023) offs[N_NODES] = part[1023];
}

__global__ __launch_bounds__(256) void scatter_kernel(const int* __restrict__ esrc,
                                                      const int* __restrict__ edst,
                                                      const int* __restrict__ offs,
                                                      int* __restrict__ pos,
                                                      int* __restrict__ ssrc) {
    int e = blockIdx.x * 256 + threadIdx.x;
    if (e >= E_TOT) return;
    int d, s;
    if (e < N_EDGES) { d = edst[e]; s = esrc[e]; }
    else             { d = e - N_EDGES; s = d; }
    int idx = offs[d] + atomicAdd(&pos[d], 1);
    ssrc[idx] = s;
}

// ---------------- GEMM + attention scores ----------------
// h = X @ W   (K=128, M=128), als/ald fused. One wave -> 8 rows, lane -> 2 cols.
__global__ __launch_bounds__(256) void gemm128_attn(const float* __restrict__ X,
                                                    const float* __restrict__ W,
                                                    const float* __restrict__ asrc,
                                                    const float* __restrict__ adst,
                                                    float* __restrict__ H,
                                                    float* __restrict__ ALS,
                                                    float* __restrict__ ALD) {
    int wave = threadIdx.x >> 6;
    int lane = threadIdx.x & 63;
    int r0 = (blockIdx.x * 4 + wave) * 8;
    r0 = __builtin_amdgcn_readfirstlane(r0);
    if (r0 >= N_NODES) return;
    int c = lane * 2;
    int head = lane >> 4;
    float acc[8][2];
#pragma unroll
    for (int i = 0; i < 8; ++i) { acc[i][0] = 0.f; acc[i][1] = 0.f; }
    const float* x0 = X + (long)r0 * 128;
    for (int k = 0; k < 128; ++k) {
        float2 w2 = *(const float2*)(W + k * 128 + c);
#pragma unroll
        for (int i = 0; i < 8; ++i) {
            float xv = x0[i * 128 + k];
            acc[i][0] += xv * w2.x;
            acc[i][1] += xv * w2.y;
        }
    }
    float as0 = asrc[c], as1 = asrc[c + 1];
    float ad0 = adst[c], ad1 = adst[c + 1];
#pragma unroll
    for (int i = 0; i < 8; ++i) {
        int r = r0 + i;
        float h0 = acc[i][0], h1 = acc[i][1];
        *(float2*)(H + (long)r * 128 + c) = make_float2(h0, h1);
        float ps = h0 * as0 + h1 * as1;
        float pd = h0 * ad0 + h1 * ad1;
#pragma unroll
        for (int off = 8; off >= 1; off >>= 1) {
            ps += __shfl_xor(ps, off, 64);
            pd += __shfl_xor(pd, off, 64);
        }
        if ((lane & 15) == 0) {
            ALS[r * 4 + head] = ps;
            ALD[r * 4 + head] = pd;
        }
    }
}

// h2 = X @ W2  (K=128, M=32, 1 head). One wave -> 16 rows (2 half-waves x 8).
__global__ __launch_bounds__(256) void gemm32_attn(const float* __restrict__ X,
                                                   const float* __restrict__ W,
                                                   const float* __restrict__ asrc,
                                                   const float* __restrict__ adst,
                                                   float* __restrict__ H2,
                                                   float* __restrict__ ALS,
                                                   float* __restrict__ ALD) {
    int wave = threadIdx.x >> 6;
    int lane = threadIdx.x & 63;
    int col = lane & 31;
    int half = lane >> 5;
    int r0 = (blockIdx.x * 4 + wave) * 16;
    r0 = __builtin_amdgcn_readfirstlane(r0);
    if (r0 >= N_NODES) return;
    float acc[8];
#pragma unroll
    for (int i = 0; i < 8; ++i) acc[i] = 0.f;
    const float* x0 = X + (long)r0 * 128;
    for (int k = 0; k < 128; ++k) {
        float wv = W[k * 32 + col];
#pragma unroll
        for (int i = 0; i < 8; ++i) {
            float xv = x0[(i * 2 + half) * 128 + k];
            acc[i] += xv * wv;
        }
    }
    float as = asrc[col], ad = adst[col];
#pragma unroll
    for (int i = 0; i < 8; ++i) {
        int r = r0 + i * 2 + half;
        H2[r * 32 + col] = acc[i];
        float ps = acc[i] * as, pd = acc[i] * ad;
#pragma unroll
        for (int off = 16; off >= 1; off >>= 1) {
            ps += __shfl_xor(ps, off, 64);
            pd += __shfl_xor(pd, off, 64);
        }
        if (col == 0) { ALS[r] = ps; ALD[r] = pd; }
    }
}

// ---------------- Edge aggregation (softmax + weighted sum), CSR by dst ----------------
// One wave per node; lane -> 2 channels; head = lane>>4. Output gets +bias then ELU.
__global__ __launch_bounds__(256) void agg128(const float* __restrict__ H,
                                              const float* __restrict__ ALS,
                                              const float* __restrict__ ALD,
                                              const int* __restrict__ offs,
                                              const int* __restrict__ ssrc,
                                              const float* __restrict__ bias,
                                              float* __restrict__ OUT) {
    int n = blockIdx.x * 4 + (threadIdx.x >> 6);
    n = __builtin_amdgcn_readfirstlane(n);
    if (n >= N_NODES) return;
    int lane = threadIdx.x & 63;
    int c = lane * 2;
    int head = lane >> 4;
    float aldh = ALD[n * 4 + head];
    int j0 = __builtin_amdgcn_readfirstlane(offs[n]);
    int j1 = __builtin_amdgcn_readfirstlane(offs[n + 1]);
    float a0 = 0.f, a1 = 0.f, dsum = 0.f;
    for (int j = j0; j < j1; ++j) {
        int s = __builtin_amdgcn_readfirstlane(ssrc[j]);
        float e = ALS[s * 4 + head] + aldh;
        e = (e > 0.f) ? e : 0.2f * e;
        float w = __expf(e);
        dsum += w;
        float2 hv = *(const float2*)(H + (long)s * 128 + c);
        a0 += w * hv.x;
        a1 += w * hv.y;
    }
    float inv = 1.0f / dsum;
    float o0 = a0 * inv + bias[c];
    float o1 = a1 * inv + bias[c + 1];
    o0 = (o0 > 0.f) ? o0 : (__expf(o0) - 1.f);
    o1 = (o1 > 0.f) ? o1 : (__expf(o1) - 1.f);
    *(float2*)(OUT + (long)n * 128 + c) = make_float2(o0, o1);
}

// 32-channel, 1-head version; one wave handles 2 nodes (half-wave each).
__global__ __launch_bounds__(256) void agg32(const float* __restrict__ H2,
                                             const float* __restrict__ ALS,
                                             const float* __restrict__ ALD,
                                             const int* __restrict__ offs,
                                             const int* __restrict__ ssrc,
                                             const float* __restrict__ bias,
                                             float* __restrict__ OUT) {
    int wv = blockIdx.x * 4 + (threadIdx.x >> 6);
    int lane = threadIdx.x & 63;
    int col = lane & 31;
    int half = lane >> 5;
    int n = wv * 2 + half;
    if (n >= N_NODES) return;
    float aldn = ALD[n];
    int j0 = offs[n], j1 = offs[n + 1];
    float acc = 0.f, dsum = 0.f;
    for (int j = j0; j < j1; ++j) {
        int s = ssrc[j];
        float e = ALS[s] + aldn;
        e = (e > 0.f) ? e : 0.2f * e;
        float w = __expf(e);
        dsum += w;
        acc += w * H2[s * 32 + col];
    }
    float o = acc / dsum + bias[col];
    o = (o > 0.f) ? o : (__expf(o) - 1.f);
    OUT[n * 32 + col] = o;
}

// ---------------- Pooling + MLP ----------------
// batch is sorted: each 32-lane group (lane=channel) walks a contiguous chunk
// of nodes, accumulating the current graph's sum in a register and flushing
// one atomic per graph transition. ~35K atomics total vs 1.28M before.
__global__ __launch_bounds__(256) void pool_kernel(const float* __restrict__ H3,
                                                   const int* __restrict__ batch,
                                                   float* __restrict__ gsum,
                                                   float* __restrict__ gcnt) {
    const int CHUNK = 40;
    int gid = (blockIdx.x * 256 + threadIdx.x) >> 5;
    int c = threadIdx.x & 31;
    int n0 = gid * CHUNK;
    if (n0 >= N_NODES) return;
    int n1 = n0 + CHUNK;
    if (n1 > N_NODES) n1 = N_NODES;
    int cur = batch[n0];
    float acc = 0.f;
    int cnt = 0;
    for (int n = n0; n < n1; ++n) {
        int b = batch[n];
        if (b != cur) {
            atomicAdd(&gsum[cur * 32 + c], acc);
            if (c == 0) atomicAdd(&gcnt[cur], (float)cnt);
            cur = b; acc = 0.f; cnt = 0;
        }
        acc += H3[n * 32 + c];
        cnt++;
    }
    atomicAdd(&gsum[cur * 32 + c], acc);
    if (c == 0) atomicAdd(&gcnt[cur], (float)cnt);
}

__global__ __launch_bounds__(256) void mlp_kernel(const float* __restrict__ gsum,
                                                  const float* __restrict__ gcnt,
                                                  const float* __restrict__ l1w,
                                                  const float* __restrict__ l1b,
                                                  const float* __restrict__ l2w,
                                                  const float* __restrict__ l2b,
                                                  float* __restrict__ out) {
    __shared__ float g[NUM_GRAPHS * 32];
    __shared__ float t1[NUM_GRAPHS * 128];
    int tid = threadIdx.x;
    for (int i = tid; i < NUM_GRAPHS * 32; i += 256) {
        float c = gcnt[i >> 5];
        g[i] = gsum[i] / fmaxf(c, 1.0f);
    }
    __syncthreads();
    for (int i = tid; i < NUM_GRAPHS * 128; i += 256) {
        int r = i >> 7, j = i & 127;
        float a = l1b[j];
        for (int k = 0; k < 32; ++k) a += g[r * 32 + k] * l1w[k * 128 + j];
        t1[i] = fmaxf(a, 0.f);
    }
    __syncthreads();
    for (int i = tid; i < NUM_GRAPHS * 8; i += 256) {
        int r = i >> 3, j = i & 7;
        float a = l2b[j];
        for (int k = 0; k < 128; ++k) a += t1[r * 128 + k] * l2w[k * 8 + j];
        out[i] = a;
    }
}

// ---------------- host ----------------

extern "C" void kernel_launch(void* const* d_in, const int* in_sizes, int n_in,
                              void* d_out, int out_size, void* d_ws, size_t ws_size,
                              hipStream_t stream) {
    const float* x      = (const float*)d_in[0];
    const int*   eidx   = (const int*)d_in[1];
    const int*   batch  = (const int*)d_in[2];
    const float* W0     = (const float*)d_in[3];
    const float* asrc0  = (const float*)d_in[4];
    const float* adst0  = (const float*)d_in[5];
    const float* b0     = (const float*)d_in[6];
    const float* W1     = (const float*)d_in[7];
    const float* asrc1  = (const float*)d_in[8];
    const float* adst1  = (const float*)d_in[9];
    const float* b1     = (const float*)d_in[10];
    const float* W2     = (const float*)d_in[11];
    const float* asrc2  = (const float*)d_in[12];
    const float* adst2  = (const float*)d_in[13];
    const float* b2     = (const float*)d_in[14];
    const float* l1w    = (const float*)d_in[15];
    const float* l1b    = (const float*)d_in[16];
    const float* l2w    = (const float*)d_in[17];
    const float* l2b    = (const float*)d_in[18];
    float* out = (float*)d_out;

    const int* esrc = eidx;
    const int* edst = eidx + N_EDGES;

    // workspace layout
    float* bufA = (float*)d_ws;                       // N*128
    float* bufB = bufA + (long)N_NODES * 128;         // N*128
    float* ALS  = bufB + (long)N_NODES * 128;         // N*4
    float* ALD  = ALS + N_NODES * 4;                  // N*4
    int* counts = (int*)(ALD + N_NODES * 4);          // N
    int* pos    = counts + N_NODES;                   // N
    float* gsum = (float*)(pos + N_NODES);            // 64*32
    float* gcnt = gsum + NUM_GRAPHS * 32;             // 64
    int* offs   = (int*)(gcnt + NUM_GRAPHS);          // N+1
    int* ssrc   = offs + (N_NODES + 1);               // E_TOT
    // reuse bufA for the 32-ch stage (bufA free after agg1 consumed it)
    float* h2a = bufA;                                // N*32
    float* h2b = bufA + (long)N_NODES * 32;           // N*32

    // zero counts, pos, gsum, gcnt (contiguous region)
    size_t zero_bytes = (size_t)(2 * N_NODES) * 4 + (NUM_GRAPHS * 32 + NUM_GRAPHS) * 4;
    hipMemsetAsync(counts, 0, zero_bytes, stream);

    int eblocks = (E_TOT + 255) / 256;
    hist_kernel<<<eblocks, 256, 0, stream>>>(edst, counts);
    scan_kernel<<<1, 1024, 0, stream>>>(counts, offs);
    scatter_kernel<<<eblocks, 256, 0, stream>>>(esrc, edst, offs, pos, ssrc);

    // layer 0: x[40000,128] @ W0 -> bufA, agg -> bufB (+b0, ELU)
    gemm128_attn<<<1250, 256, 0, stream>>>(x, W0, asrc0, adst0, bufA, ALS, ALD);
    agg128<<<10000, 256, 0, stream>>>(bufA, ALS, ALD, offs, ssrc, b0, bufB);

    // layer 1: bufB @ W1 -> bufA, agg -> bufB (+b1, ELU)
    gemm128_attn<<<1250, 256, 0, stream>>>(bufB, W1, asrc1, adst1, bufA, ALS, ALD);
    agg128<<<10000, 256, 0, stream>>>(bufA, ALS, ALD, offs, ssrc, b1, bufB);

    // layer 2: bufB @ W2 -> h2a (N,32), agg -> h2b (+b2, ELU)
    gemm32_attn<<<625, 256, 0, stream>>>(bufB, W2, asrc2, adst2, h2a, ALS, ALD);
    agg32<<<5000, 256, 0, stream>>>(h2a, ALS, ALD, offs, ssrc, b2, h2b);

    // pool + MLP
    pool_kernel<<<125, 256, 0, stream>>>(h2b, batch, gsum, gcnt);
    mlp_kernel<<<1, 256, 0, stream>>>(gsum, gcnt, l1w, l1b, l2w, l2b, out);
}

// Round 3
// 419.050 us; speedup vs baseline: 1.8524x; 1.2075x over previous
//
#include <hip/hip_runtime.h>
#include <hip/hip_bf16.h>

#define N_NODES 40000
#define N_EDGES 640000
#define E_TOT   (N_EDGES + N_NODES)
#define NUM_GRAPHS 64
#define SCAN_BLOCKS 160
#define SCAN_CHUNK  250   // 160*250 = 40000

// ---------------- CSR build ----------------

__global__ __launch_bounds__(256) void hist_kernel(const int* __restrict__ edst,
                                                   int* __restrict__ counts) {
    int e = blockIdx.x * 256 + threadIdx.x;
    if (e >= E_TOT) return;
    int d = (e < N_EDGES) ? edst[e] : (e - N_EDGES);
    atomicAdd(&counts[d], 1);
}

// phase 1: per-block sums of 250 contiguous counts (coalesced)
__global__ __launch_bounds__(256) void bsum_kernel(const int* __restrict__ counts,
                                                   int* __restrict__ bsum) {
    __shared__ int ws[4];
    int b = blockIdx.x, tid = threadIdx.x;
    int idx = b * SCAN_CHUNK + tid;
    int v = (tid < SCAN_CHUNK) ? counts[idx] : 0;
#pragma unroll
    for (int off = 32; off >= 1; off >>= 1) v += __shfl_down(v, off, 64);
    if ((tid & 63) == 0) ws[tid >> 6] = v;
    __syncthreads();
    if (tid == 0) bsum[b] = ws[0] + ws[1] + ws[2] + ws[3];
}

// phase 2: exclusive scan of the 160 block sums (single small block)
__global__ __launch_bounds__(256) void bscan_kernel(const int* __restrict__ bsum,
                                                    int* __restrict__ bofs) {
    __shared__ int s[256];
    int tid = threadIdx.x;
    int v = (tid < SCAN_BLOCKS) ? bsum[tid] : 0;
    s[tid] = v;
    __syncthreads();
    for (int off = 1; off < 256; off <<= 1) {
        int t = (tid >= off) ? s[tid - off] : 0;
        __syncthreads();
        s[tid] += t;
        __syncthreads();
    }
    if (tid < SCAN_BLOCKS) bofs[tid] = s[tid] - v;  // exclusive
}

// phase 3: local exclusive scan + block base -> offs
__global__ __launch_bounds__(256) void boffs_kernel(const int* __restrict__ counts,
                                                    const int* __restrict__ bofs,
                                                    int* __restrict__ offs) {
    __shared__ int s[256];
    int b = blockIdx.x, tid = threadIdx.x;
    int idx = b * SCAN_CHUNK + tid;
    int v = (tid < SCAN_CHUNK) ? counts[idx] : 0;
    s[tid] = v;
    __syncthreads();
    for (int off = 1; off < 256; off <<= 1) {
        int t = (tid >= off) ? s[tid - off] : 0;
        __syncthreads();
        s[tid] += t;
        __syncthreads();
    }
    int incl = s[tid];
    int base = bofs[b];
    if (tid < SCAN_CHUNK) {
        offs[idx] = base + incl - v;
        if (idx == N_NODES - 1) offs[N_NODES] = base + incl;
    }
}

__global__ __launch_bounds__(256) void scatter_kernel(const int* __restrict__ esrc,
                                                      const int* __restrict__ edst,
                                                      const int* __restrict__ offs,
                                                      int* __restrict__ pos,
                                                      int* __restrict__ ssrc) {
    int e = blockIdx.x * 256 + threadIdx.x;
    if (e >= E_TOT) return;
    int d, s;
    if (e < N_EDGES) { d = edst[e]; s = esrc[e]; }
    else             { d = e - N_EDGES; s = d; }
    int idx = offs[d] + atomicAdd(&pos[d], 1);
    ssrc[idx] = s;
}

// ---------------- GEMM + attention scores ----------------
// h = X @ W   (K=128, M=128), als/ald fused. One wave -> 8 rows, lane -> 2 cols.
__global__ __launch_bounds__(256) void gemm128_attn(const float* __restrict__ X,
                                                    const float* __restrict__ W,
                                                    const float* __restrict__ asrc,
                                                    const float* __restrict__ adst,
                                                    float* __restrict__ H,
                                                    float* __restrict__ ALS,
                                                    float* __restrict__ ALD) {
    int wave = threadIdx.x >> 6;
    int lane = threadIdx.x & 63;
    int r0 = (blockIdx.x * 4 + wave) * 8;
    r0 = __builtin_amdgcn_readfirstlane(r0);
    if (r0 >= N_NODES) return;
    int c = lane * 2;
    int head = lane >> 4;
    float acc[8][2];
#pragma unroll
    for (int i = 0; i < 8; ++i) { acc[i][0] = 0.f; acc[i][1] = 0.f; }
    const float* x0 = X + (long)r0 * 128;
    for (int k = 0; k < 128; ++k) {
        float2 w2 = *(const float2*)(W + k * 128 + c);
#pragma unroll
        for (int i = 0; i < 8; ++i) {
            float xv = x0[i * 128 + k];
            acc[i][0] += xv * w2.x;
            acc[i][1] += xv * w2.y;
        }
    }
    float as0 = asrc[c], as1 = asrc[c + 1];
    float ad0 = adst[c], ad1 = adst[c + 1];
#pragma unroll
    for (int i = 0; i < 8; ++i) {
        int r = r0 + i;
        float h0 = acc[i][0], h1 = acc[i][1];
        *(float2*)(H + (long)r * 128 + c) = make_float2(h0, h1);
        float ps = h0 * as0 + h1 * as1;
        float pd = h0 * ad0 + h1 * ad1;
#pragma unroll
        for (int off = 8; off >= 1; off >>= 1) {
            ps += __shfl_xor(ps, off, 64);
            pd += __shfl_xor(pd, off, 64);
        }
        if ((lane & 15) == 0) {
            ALS[r * 4 + head] = ps;
            ALD[r * 4 + head] = pd;
        }
    }
}

// h2 = X @ W2  (K=128, M=32, 1 head). One wave -> 16 rows (2 half-waves x 8).
__global__ __launch_bounds__(256) void gemm32_attn(const float* __restrict__ X,
                                                   const float* __restrict__ W,
                                                   const float* __restrict__ asrc,
                                                   const float* __restrict__ adst,
                                                   float* __restrict__ H2,
                                                   float* __restrict__ ALS,
                                                   float* __restrict__ ALD) {
    int wave = threadIdx.x >> 6;
    int lane = threadIdx.x & 63;
    int col = lane & 31;
    int half = lane >> 5;
    int r0 = (blockIdx.x * 4 + wave) * 16;
    r0 = __builtin_amdgcn_readfirstlane(r0);
    if (r0 >= N_NODES) return;
    float acc[8];
#pragma unroll
    for (int i = 0; i < 8; ++i) acc[i] = 0.f;
    const float* x0 = X + (long)r0 * 128;
    for (int k = 0; k < 128; ++k) {
        float wv = W[k * 32 + col];
#pragma unroll
        for (int i = 0; i < 8; ++i) {
            float xv = x0[(i * 2 + half) * 128 + k];
            acc[i] += xv * wv;
        }
    }
    float as = asrc[col], ad = adst[col];
#pragma unroll
    for (int i = 0; i < 8; ++i) {
        int r = r0 + i * 2 + half;
        H2[r * 32 + col] = acc[i];
        float ps = acc[i] * as, pd = acc[i] * ad;
#pragma unroll
        for (int off = 16; off >= 1; off >>= 1) {
            ps += __shfl_xor(ps, off, 64);
            pd += __shfl_xor(pd, off, 64);
        }
        if (col == 0) { ALS[r] = ps; ALD[r] = pd; }
    }
}

// ---------------- Edge aggregation (softmax + weighted sum), CSR by dst ----------------
// One wave per node; lane -> 2 channels; head = lane>>4. Edge loop unrolled x2
// with independent accumulators for memory-level parallelism.
__global__ __launch_bounds__(256) void agg128(const float* __restrict__ H,
                                              const float* __restrict__ ALS,
                                              const float* __restrict__ ALD,
                                              const int* __restrict__ offs,
                                              const int* __restrict__ ssrc,
                                              const float* __restrict__ bias,
                                              float* __restrict__ OUT) {
    int n = blockIdx.x * 4 + (threadIdx.x >> 6);
    n = __builtin_amdgcn_readfirstlane(n);
    if (n >= N_NODES) return;
    int lane = threadIdx.x & 63;
    int c = lane * 2;
    int head = lane >> 4;
    float aldh = ALD[n * 4 + head];
    int j0 = __builtin_amdgcn_readfirstlane(offs[n]);
    int j1 = __builtin_amdgcn_readfirstlane(offs[n + 1]);
    float a0 = 0.f, a1 = 0.f, dsum = 0.f;
    float b0a = 0.f, b1a = 0.f, dsum2 = 0.f;
    int j = j0;
    for (; j + 1 < j1; j += 2) {
        int s0 = __builtin_amdgcn_readfirstlane(ssrc[j]);
        int s1 = __builtin_amdgcn_readfirstlane(ssrc[j + 1]);
        float e0 = ALS[s0 * 4 + head] + aldh;
        float e1 = ALS[s1 * 4 + head] + aldh;
        e0 = (e0 > 0.f) ? e0 : 0.2f * e0;
        e1 = (e1 > 0.f) ? e1 : 0.2f * e1;
        float w0 = __expf(e0), w1 = __expf(e1);
        float2 h0 = *(const float2*)(H + (long)s0 * 128 + c);
        float2 h1 = *(const float2*)(H + (long)s1 * 128 + c);
        dsum  += w0; dsum2 += w1;
        a0 += w0 * h0.x; a1 += w0 * h0.y;
        b0a += w1 * h1.x; b1a += w1 * h1.y;
    }
    if (j < j1) {
        int s = __builtin_amdgcn_readfirstlane(ssrc[j]);
        float e = ALS[s * 4 + head] + aldh;
        e = (e > 0.f) ? e : 0.2f * e;
        float w = __expf(e);
        float2 hv = *(const float2*)(H + (long)s * 128 + c);
        dsum += w;
        a0 += w * hv.x; a1 += w * hv.y;
    }
    a0 += b0a; a1 += b1a; dsum += dsum2;
    float inv = 1.0f / dsum;
    float o0 = a0 * inv + bias[c];
    float o1 = a1 * inv + bias[c + 1];
    o0 = (o0 > 0.f) ? o0 : (__expf(o0) - 1.f);
    o1 = (o1 > 0.f) ? o1 : (__expf(o1) - 1.f);
    *(float2*)(OUT + (long)n * 128 + c) = make_float2(o0, o1);
}

// 32-channel, 1-head version; one wave handles 2 nodes (half-wave each).
__global__ __launch_bounds__(256) void agg32(const float* __restrict__ H2,
                                             const float* __restrict__ ALS,
                                             const float* __restrict__ ALD,
                                             const int* __restrict__ offs,
                                             const int* __restrict__ ssrc,
                                             const float* __restrict__ bias,
                                             float* __restrict__ OUT) {
    int wv = blockIdx.x * 4 + (threadIdx.x >> 6);
    int lane = threadIdx.x & 63;
    int col = lane & 31;
    int half = lane >> 5;
    int n = wv * 2 + half;
    if (n >= N_NODES) return;
    float aldn = ALD[n];
    int j0 = offs[n], j1 = offs[n + 1];
    float acc = 0.f, dsum = 0.f;
    float acc2 = 0.f, dsum2 = 0.f;
    int j = j0;
    for (; j + 1 < j1; j += 2) {
        int s0 = ssrc[j], s1 = ssrc[j + 1];
        float e0 = ALS[s0] + aldn;
        float e1 = ALS[s1] + aldn;
        e0 = (e0 > 0.f) ? e0 : 0.2f * e0;
        e1 = (e1 > 0.f) ? e1 : 0.2f * e1;
        float w0 = __expf(e0), w1 = __expf(e1);
        dsum += w0; dsum2 += w1;
        acc += w0 * H2[s0 * 32 + col];
        acc2 += w1 * H2[s1 * 32 + col];
    }
    if (j < j1) {
        int s = ssrc[j];
        float e = ALS[s] + aldn;
        e = (e > 0.f) ? e : 0.2f * e;
        float w = __expf(e);
        dsum += w;
        acc += w * H2[s * 32 + col];
    }
    acc += acc2; dsum += dsum2;
    float o = acc / dsum + bias[col];
    o = (o > 0.f) ? o : (__expf(o) - 1.f);
    OUT[n * 32 + col] = o;
}

// ---------------- Pooling + MLP ----------------
__global__ __launch_bounds__(256) void pool_kernel(const float* __restrict__ H3,
                                                   const int* __restrict__ batch,
                                                   float* __restrict__ gsum,
                                                   float* __restrict__ gcnt) {
    const int CHUNK = 40;
    int gid = (blockIdx.x * 256 + threadIdx.x) >> 5;
    int c = threadIdx.x & 31;
    int n0 = gid * CHUNK;
    if (n0 >= N_NODES) return;
    int n1 = n0 + CHUNK;
    if (n1 > N_NODES) n1 = N_NODES;
    int cur = batch[n0];
    float acc = 0.f;
    int cnt = 0;
    for (int n = n0; n < n1; ++n) {
        int b = batch[n];
        if (b != cur) {
            atomicAdd(&gsum[cur * 32 + c], acc);
            if (c == 0) atomicAdd(&gcnt[cur], (float)cnt);
            cur = b; acc = 0.f; cnt = 0;
        }
        acc += H3[n * 32 + c];
        cnt++;
    }
    atomicAdd(&gsum[cur * 32 + c], acc);
    if (c == 0) atomicAdd(&gcnt[cur], (float)cnt);
}

__global__ __launch_bounds__(256) void mlp_kernel(const float* __restrict__ gsum,
                                                  const float* __restrict__ gcnt,
                                                  const float* __restrict__ l1w,
                                                  const float* __restrict__ l1b,
                                                  const float* __restrict__ l2w,
                                                  const float* __restrict__ l2b,
                                                  float* __restrict__ out) {
    __shared__ float g[NUM_GRAPHS * 32];
    __shared__ float t1[NUM_GRAPHS * 128];
    int tid = threadIdx.x;
    for (int i = tid; i < NUM_GRAPHS * 32; i += 256) {
        float c = gcnt[i >> 5];
        g[i] = gsum[i] / fmaxf(c, 1.0f);
    }
    __syncthreads();
    for (int i = tid; i < NUM_GRAPHS * 128; i += 256) {
        int r = i >> 7, j = i & 127;
        float a = l1b[j];
        for (int k = 0; k < 32; ++k) a += g[r * 32 + k] * l1w[k * 128 + j];
        t1[i] = fmaxf(a, 0.f);
    }
    __syncthreads();
    for (int i = tid; i < NUM_GRAPHS * 8; i += 256) {
        int r = i >> 3, j = i & 7;
        float a = l2b[j];
        for (int k = 0; k < 128; ++k) a += t1[r * 128 + k] * l2w[k * 8 + j];
        out[i] = a;
    }
}

// ---------------- host ----------------

extern "C" void kernel_launch(void* const* d_in, const int* in_sizes, int n_in,
                              void* d_out, int out_size, void* d_ws, size_t ws_size,
                              hipStream_t stream) {
    const float* x      = (const float*)d_in[0];
    const int*   eidx   = (const int*)d_in[1];
    const int*   batch  = (const int*)d_in[2];
    const float* W0     = (const float*)d_in[3];
    const float* asrc0  = (const float*)d_in[4];
    const float* adst0  = (const float*)d_in[5];
    const float* b0     = (const float*)d_in[6];
    const float* W1     = (const float*)d_in[7];
    const float* asrc1  = (const float*)d_in[8];
    const float* adst1  = (const float*)d_in[9];
    const float* b1     = (const float*)d_in[10];
    const float* W2     = (const float*)d_in[11];
    const float* asrc2  = (const float*)d_in[12];
    const float* adst2  = (const float*)d_in[13];
    const float* b2     = (const float*)d_in[14];
    const float* l1w    = (const float*)d_in[15];
    const float* l1b    = (const float*)d_in[16];
    const float* l2w    = (const float*)d_in[17];
    const float* l2b    = (const float*)d_in[18];
    float* out = (float*)d_out;

    const int* esrc = eidx;
    const int* edst = eidx + N_EDGES;

    // workspace layout
    float* bufA = (float*)d_ws;                       // N*128
    float* bufB = bufA + (long)N_NODES * 128;         // N*128
    float* ALS  = bufB + (long)N_NODES * 128;         // N*4
    float* ALD  = ALS + N_NODES * 4;                  // N*4
    int* counts = (int*)(ALD + N_NODES * 4);          // N
    int* pos    = counts + N_NODES;                   // N
    float* gsum = (float*)(pos + N_NODES);            // 64*32
    float* gcnt = gsum + NUM_GRAPHS * 32;             // 64
    int* offs   = (int*)(gcnt + NUM_GRAPHS);          // N+1
    int* ssrc   = offs + (N_NODES + 1);               // E_TOT
    int* bsum   = ssrc + E_TOT;                       // SCAN_BLOCKS
    int* bofs   = bsum + SCAN_BLOCKS;                 // SCAN_BLOCKS
    // reuse bufA for the 32-ch stage (bufA free after agg1 consumed it)
    float* h2a = bufA;                                // N*32
    float* h2b = bufA + (long)N_NODES * 32;           // N*32

    // zero counts, pos, gsum, gcnt (contiguous region)
    size_t zero_bytes = (size_t)(2 * N_NODES) * 4 + (NUM_GRAPHS * 32 + NUM_GRAPHS) * 4;
    hipMemsetAsync(counts, 0, zero_bytes, stream);

    int eblocks = (E_TOT + 255) / 256;
    hist_kernel<<<eblocks, 256, 0, stream>>>(edst, counts);
    bsum_kernel<<<SCAN_BLOCKS, 256, 0, stream>>>(counts, bsum);
    bscan_kernel<<<1, 256, 0, stream>>>(bsum, bofs);
    boffs_kernel<<<SCAN_BLOCKS, 256, 0, stream>>>(counts, bofs, offs);
    scatter_kernel<<<eblocks, 256, 0, stream>>>(esrc, edst, offs, pos, ssrc);

    // layer 0: x[40000,128] @ W0 -> bufA, agg -> bufB (+b0, ELU)
    gemm128_attn<<<1250, 256, 0, stream>>>(x, W0, asrc0, adst0, bufA, ALS, ALD);
    agg128<<<10000, 256, 0, stream>>>(bufA, ALS, ALD, offs, ssrc, b0, bufB);

    // layer 1: bufB @ W1 -> bufA, agg -> bufB (+b1, ELU)
    gemm128_attn<<<1250, 256, 0, stream>>>(bufB, W1, asrc1, adst1, bufA, ALS, ALD);
    agg128<<<10000, 256, 0, stream>>>(bufA, ALS, ALD, offs, ssrc, b1, bufB);

    // layer 2: bufB @ W2 -> h2a (N,32), agg -> h2b (+b2, ELU)
    gemm32_attn<<<625, 256, 0, stream>>>(bufB, W2, asrc2, adst2, h2a, ALS, ALD);
    agg32<<<5000, 256, 0, stream>>>(h2a, ALS, ALD, offs, ssrc, b2, h2b);

    // pool + MLP
    pool_kernel<<<125, 256, 0, stream>>>(h2b, batch, gsum, gcnt);
    mlp_kernel<<<1, 256, 0, stream>>>(gsum, gcnt, l1w, l1b, l2w, l2b, out);
}

// Round 4
// 371.511 us; speedup vs baseline: 2.0894x; 1.1280x over previous
//
#include <hip/hip_runtime.h>
#include <hip/hip_bf16.h>

#define N_NODES 40000
#define N_EDGES 640000
#define E_TOT   (N_EDGES + N_NODES)
#define NUM_GRAPHS 64
#define SCAN_BLOCKS 160
#define SCAN_CHUNK  250   // 160*250 = 40000

__device__ inline float bf2f(unsigned short u) {
    union { unsigned int i; float f; } v; v.i = ((unsigned int)u) << 16; return v.f;
}
__device__ inline unsigned short f2bf(float f) {
    union { float f; unsigned int i; } v; v.f = f;
    unsigned int r = v.i + 0x7FFF + ((v.i >> 16) & 1);
    return (unsigned short)(r >> 16);
}

// ---------------- CSR build ----------------

__global__ __launch_bounds__(256) void hist_kernel(const int* __restrict__ edst,
                                                   int* __restrict__ counts) {
    int e = blockIdx.x * 256 + threadIdx.x;
    if (e >= E_TOT) return;
    int d = (e < N_EDGES) ? edst[e] : (e - N_EDGES);
    atomicAdd(&counts[d], 1);
}

__global__ __launch_bounds__(256) void bsum_kernel(const int* __restrict__ counts,
                                                   int* __restrict__ bsum) {
    __shared__ int ws[4];
    int b = blockIdx.x, tid = threadIdx.x;
    int idx = b * SCAN_CHUNK + tid;
    int v = (tid < SCAN_CHUNK) ? counts[idx] : 0;
#pragma unroll
    for (int off = 32; off >= 1; off >>= 1) v += __shfl_down(v, off, 64);
    if ((tid & 63) == 0) ws[tid >> 6] = v;
    __syncthreads();
    if (tid == 0) bsum[b] = ws[0] + ws[1] + ws[2] + ws[3];
}

__global__ __launch_bounds__(256) void bscan_kernel(const int* __restrict__ bsum,
                                                    int* __restrict__ bofs) {
    __shared__ int s[256];
    int tid = threadIdx.x;
    int v = (tid < SCAN_BLOCKS) ? bsum[tid] : 0;
    s[tid] = v;
    __syncthreads();
    for (int off = 1; off < 256; off <<= 1) {
        int t = (tid >= off) ? s[tid - off] : 0;
        __syncthreads();
        s[tid] += t;
        __syncthreads();
    }
    if (tid < SCAN_BLOCKS) bofs[tid] = s[tid] - v;  // exclusive
}

__global__ __launch_bounds__(256) void boffs_kernel(const int* __restrict__ counts,
                                                    const int* __restrict__ bofs,
                                                    int* __restrict__ offs) {
    __shared__ int s[256];
    int b = blockIdx.x, tid = threadIdx.x;
    int idx = b * SCAN_CHUNK + tid;
    int v = (tid < SCAN_CHUNK) ? counts[idx] : 0;
    s[tid] = v;
    __syncthreads();
    for (int off = 1; off < 256; off <<= 1) {
        int t = (tid >= off) ? s[tid - off] : 0;
        __syncthreads();
        s[tid] += t;
        __syncthreads();
    }
    int incl = s[tid];
    int base = bofs[b];
    if (tid < SCAN_CHUNK) {
        offs[idx] = base + incl - v;
        if (idx == N_NODES - 1) offs[N_NODES] = base + incl;
    }
}

__global__ __launch_bounds__(256) void scatter_kernel(const int* __restrict__ esrc,
                                                      const int* __restrict__ edst,
                                                      const int* __restrict__ offs,
                                                      int* __restrict__ pos,
                                                      int* __restrict__ ssrc) {
    int e = blockIdx.x * 256 + threadIdx.x;
    if (e >= E_TOT) return;
    int d, s;
    if (e < N_EDGES) { d = edst[e]; s = esrc[e]; }
    else             { d = e - N_EDGES; s = d; }
    int idx = offs[d] + atomicAdd(&pos[d], 1);
    ssrc[idx] = s;
}

// ---------------- GEMM + attention scores ----------------
// h = X @ W (K=128, M=128). One wave -> 8 rows, lane -> 2 cols.
// k-unrolled x8: 8 independent W float2 loads in flight + wave-uniform
// float4 x loads (s_load_dwordx4). H stored bf16 for the gather stage.
__global__ __launch_bounds__(256) void gemm128_attn(const float* __restrict__ X,
                                                    const float* __restrict__ W,
                                                    const float* __restrict__ asrc,
                                                    const float* __restrict__ adst,
                                                    unsigned short* __restrict__ Hb,
                                                    float* __restrict__ ALS,
                                                    float* __restrict__ ALD) {
    int wave = threadIdx.x >> 6;
    int lane = threadIdx.x & 63;
    int r0 = (blockIdx.x * 4 + wave) * 8;
    r0 = __builtin_amdgcn_readfirstlane(r0);
    if (r0 >= N_NODES) return;
    int c = lane * 2;
    int head = lane >> 4;
    float acc[8][2];
#pragma unroll
    for (int i = 0; i < 8; ++i) { acc[i][0] = 0.f; acc[i][1] = 0.f; }
    const float* x0 = X + (long)r0 * 128;
    for (int k = 0; k < 128; k += 8) {
        float2 w[8];
#pragma unroll
        for (int u = 0; u < 8; ++u)
            w[u] = *(const float2*)(W + (k + u) * 128 + c);
#pragma unroll
        for (int i = 0; i < 8; ++i) {
            float4 xa = *(const float4*)(x0 + i * 128 + k);
            float4 xb = *(const float4*)(x0 + i * 128 + k + 4);
            acc[i][0] += xa.x * w[0].x; acc[i][1] += xa.x * w[0].y;
            acc[i][0] += xa.y * w[1].x; acc[i][1] += xa.y * w[1].y;
            acc[i][0] += xa.z * w[2].x; acc[i][1] += xa.z * w[2].y;
            acc[i][0] += xa.w * w[3].x; acc[i][1] += xa.w * w[3].y;
            acc[i][0] += xb.x * w[4].x; acc[i][1] += xb.x * w[4].y;
            acc[i][0] += xb.y * w[5].x; acc[i][1] += xb.y * w[5].y;
            acc[i][0] += xb.z * w[6].x; acc[i][1] += xb.z * w[6].y;
            acc[i][0] += xb.w * w[7].x; acc[i][1] += xb.w * w[7].y;
        }
    }
    float as0 = asrc[c], as1 = asrc[c + 1];
    float ad0 = adst[c], ad1 = adst[c + 1];
#pragma unroll
    for (int i = 0; i < 8; ++i) {
        int r = r0 + i;
        float h0 = acc[i][0], h1 = acc[i][1];
        ushort2 hb; hb.x = f2bf(h0); hb.y = f2bf(h1);
        *(ushort2*)(Hb + (long)r * 128 + c) = hb;
        float ps = h0 * as0 + h1 * as1;
        float pd = h0 * ad0 + h1 * ad1;
#pragma unroll
        for (int off = 8; off >= 1; off >>= 1) {
            ps += __shfl_xor(ps, off, 64);
            pd += __shfl_xor(pd, off, 64);
        }
        if ((lane & 15) == 0) {
            ALS[r * 4 + head] = ps;
            ALD[r * 4 + head] = pd;
        }
    }
}

// h2 = X @ W2 (K=128, M=32, 1 head). One wave -> 8 rows, col = lane&31
// (both 32-lane halves compute duplicates so x loads stay wave-uniform).
__global__ __launch_bounds__(256) void gemm32_attn(const float* __restrict__ X,
                                                   const float* __restrict__ W,
                                                   const float* __restrict__ asrc,
                                                   const float* __restrict__ adst,
                                                   unsigned short* __restrict__ H2b,
                                                   float* __restrict__ ALS,
                                                   float* __restrict__ ALD) {
    int wave = threadIdx.x >> 6;
    int lane = threadIdx.x & 63;
    int col = lane & 31;
    int r0 = (blockIdx.x * 4 + wave) * 8;
    r0 = __builtin_amdgcn_readfirstlane(r0);
    if (r0 >= N_NODES) return;
    float acc[8];
#pragma unroll
    for (int i = 0; i < 8; ++i) acc[i] = 0.f;
    const float* x0 = X + (long)r0 * 128;
    for (int k = 0; k < 128; k += 8) {
        float w[8];
#pragma unroll
        for (int u = 0; u < 8; ++u) w[u] = W[(k + u) * 32 + col];
#pragma unroll
        for (int i = 0; i < 8; ++i) {
            float4 xa = *(const float4*)(x0 + i * 128 + k);
            float4 xb = *(const float4*)(x0 + i * 128 + k + 4);
            acc[i] += xa.x * w[0]; acc[i] += xa.y * w[1];
            acc[i] += xa.z * w[2]; acc[i] += xa.w * w[3];
            acc[i] += xb.x * w[4]; acc[i] += xb.y * w[5];
            acc[i] += xb.z * w[6]; acc[i] += xb.w * w[7];
        }
    }
    float as = asrc[col], ad = adst[col];
#pragma unroll
    for (int i = 0; i < 8; ++i) {
        int r = r0 + i;
        float ps = acc[i] * as, pd = acc[i] * ad;
#pragma unroll
        for (int off = 16; off >= 1; off >>= 1) {
            ps += __shfl_xor(ps, off, 64);
            pd += __shfl_xor(pd, off, 64);
        }
        if (lane == 0) { ALS[r] = ps; ALD[r] = pd; }
        if (lane < 32) H2b[r * 32 + col] = f2bf(acc[i]);
    }
}

// ---------------- Edge aggregation (softmax + weighted sum), CSR by dst ----------------
// One wave per node; lane -> 2 bf16 channels; head = lane>>4. Unrolled x2.
__global__ __launch_bounds__(256) void agg128(const unsigned short* __restrict__ Hb,
                                              const float* __restrict__ ALS,
                                              const float* __restrict__ ALD,
                                              const int* __restrict__ offs,
                                              const int* __restrict__ ssrc,
                                              const float* __restrict__ bias,
                                              float* __restrict__ OUT) {
    int n = blockIdx.x * 4 + (threadIdx.x >> 6);
    n = __builtin_amdgcn_readfirstlane(n);
    if (n >= N_NODES) return;
    int lane = threadIdx.x & 63;
    int c = lane * 2;
    int head = lane >> 4;
    float aldh = ALD[n * 4 + head];
    int j0 = __builtin_amdgcn_readfirstlane(offs[n]);
    int j1 = __builtin_amdgcn_readfirstlane(offs[n + 1]);
    float a0 = 0.f, a1 = 0.f, dsum = 0.f;
    float b0a = 0.f, b1a = 0.f, dsum2 = 0.f;
    int j = j0;
    for (; j + 1 < j1; j += 2) {
        int s0 = __builtin_amdgcn_readfirstlane(ssrc[j]);
        int s1 = __builtin_amdgcn_readfirstlane(ssrc[j + 1]);
        float e0 = ALS[s0 * 4 + head] + aldh;
        float e1 = ALS[s1 * 4 + head] + aldh;
        e0 = (e0 > 0.f) ? e0 : 0.2f * e0;
        e1 = (e1 > 0.f) ? e1 : 0.2f * e1;
        float w0 = __expf(e0), w1 = __expf(e1);
        ushort2 h0 = *(const ushort2*)(Hb + (long)s0 * 128 + c);
        ushort2 h1 = *(const ushort2*)(Hb + (long)s1 * 128 + c);
        dsum  += w0; dsum2 += w1;
        a0 += w0 * bf2f(h0.x); a1 += w0 * bf2f(h0.y);
        b0a += w1 * bf2f(h1.x); b1a += w1 * bf2f(h1.y);
    }
    if (j < j1) {
        int s = __builtin_amdgcn_readfirstlane(ssrc[j]);
        float e = ALS[s * 4 + head] + aldh;
        e = (e > 0.f) ? e : 0.2f * e;
        float w = __expf(e);
        ushort2 hv = *(const ushort2*)(Hb + (long)s * 128 + c);
        dsum += w;
        a0 += w * bf2f(hv.x); a1 += w * bf2f(hv.y);
    }
    a0 += b0a; a1 += b1a; dsum += dsum2;
    float inv = 1.0f / dsum;
    float o0 = a0 * inv + bias[c];
    float o1 = a1 * inv + bias[c + 1];
    o0 = (o0 > 0.f) ? o0 : (__expf(o0) - 1.f);
    o1 = (o1 > 0.f) ? o1 : (__expf(o1) - 1.f);
    *(float2*)(OUT + (long)n * 128 + c) = make_float2(o0, o1);
}

// 32-channel, 1-head version; one wave handles 2 nodes (half-wave each).
__global__ __launch_bounds__(256) void agg32(const unsigned short* __restrict__ H2b,
                                             const float* __restrict__ ALS,
                                             const float* __restrict__ ALD,
                                             const int* __restrict__ offs,
                                             const int* __restrict__ ssrc,
                                             const float* __restrict__ bias,
                                             float* __restrict__ OUT) {
    int wv = blockIdx.x * 4 + (threadIdx.x >> 6);
    int lane = threadIdx.x & 63;
    int col = lane & 31;
    int half = lane >> 5;
    int n = wv * 2 + half;
    if (n >= N_NODES) return;
    float aldn = ALD[n];
    int j0 = offs[n], j1 = offs[n + 1];
    float acc = 0.f, dsum = 0.f;
    float acc2 = 0.f, dsum2 = 0.f;
    int j = j0;
    for (; j + 1 < j1; j += 2) {
        int s0 = ssrc[j], s1 = ssrc[j + 1];
        float e0 = ALS[s0] + aldn;
        float e1 = ALS[s1] + aldn;
        e0 = (e0 > 0.f) ? e0 : 0.2f * e0;
        e1 = (e1 > 0.f) ? e1 : 0.2f * e1;
        float w0 = __expf(e0), w1 = __expf(e1);
        dsum += w0; dsum2 += w1;
        acc += w0 * bf2f(H2b[s0 * 32 + col]);
        acc2 += w1 * bf2f(H2b[s1 * 32 + col]);
    }
    if (j < j1) {
        int s = ssrc[j];
        float e = ALS[s] + aldn;
        e = (e > 0.f) ? e : 0.2f * e;
        float w = __expf(e);
        dsum += w;
        acc += w * bf2f(H2b[s * 32 + col]);
    }
    acc += acc2; dsum += dsum2;
    float o = acc / dsum + bias[col];
    o = (o > 0.f) ? o : (__expf(o) - 1.f);
    OUT[n * 32 + col] = o;
}

// ---------------- Pooling + MLP ----------------
__global__ __launch_bounds__(256) void pool_kernel(const float* __restrict__ H3,
                                                   const int* __restrict__ batch,
                                                   float* __restrict__ gsum,
                                                   float* __restrict__ gcnt) {
    const int CHUNK = 40;
    int gid = (blockIdx.x * 256 + threadIdx.x) >> 5;
    int c = threadIdx.x & 31;
    int n0 = gid * CHUNK;
    if (n0 >= N_NODES) return;
    int n1 = n0 + CHUNK;
    if (n1 > N_NODES) n1 = N_NODES;
    int cur = batch[n0];
    float acc = 0.f;
    int cnt = 0;
    for (int n = n0; n < n1; ++n) {
        int b = batch[n];
        if (b != cur) {
            atomicAdd(&gsum[cur * 32 + c], acc);
            if (c == 0) atomicAdd(&gcnt[cur], (float)cnt);
            cur = b; acc = 0.f; cnt = 0;
        }
        acc += H3[n * 32 + c];
        cnt++;
    }
    atomicAdd(&gsum[cur * 32 + c], acc);
    if (c == 0) atomicAdd(&gcnt[cur], (float)cnt);
}

__global__ __launch_bounds__(256) void mlp_kernel(const float* __restrict__ gsum,
                                                  const float* __restrict__ gcnt,
                                                  const float* __restrict__ l1w,
                                                  const float* __restrict__ l1b,
                                                  const float* __restrict__ l2w,
                                                  const float* __restrict__ l2b,
                                                  float* __restrict__ out) {
    __shared__ float g[NUM_GRAPHS * 32];
    __shared__ float t1[NUM_GRAPHS * 128];
    int tid = threadIdx.x;
    for (int i = tid; i < NUM_GRAPHS * 32; i += 256) {
        float c = gcnt[i >> 5];
        g[i] = gsum[i] / fmaxf(c, 1.0f);
    }
    __syncthreads();
    for (int i = tid; i < NUM_GRAPHS * 128; i += 256) {
        int r = i >> 7, j = i & 127;
        float a = l1b[j];
        for (int k = 0; k < 32; ++k) a += g[r * 32 + k] * l1w[k * 128 + j];
        t1[i] = fmaxf(a, 0.f);
    }
    __syncthreads();
    for (int i = tid; i < NUM_GRAPHS * 8; i += 256) {
        int r = i >> 3, j = i & 7;
        float a = l2b[j];
        for (int k = 0; k < 128; ++k) a += t1[r * 128 + k] * l2w[k * 8 + j];
        out[i] = a;
    }
}

// ---------------- host ----------------

extern "C" void kernel_launch(void* const* d_in, const int* in_sizes, int n_in,
                              void* d_out, int out_size, void* d_ws, size_t ws_size,
                              hipStream_t stream) {
    const float* x      = (const float*)d_in[0];
    const int*   eidx   = (const int*)d_in[1];
    const int*   batch  = (const int*)d_in[2];
    const float* W0     = (const float*)d_in[3];
    const float* asrc0  = (const float*)d_in[4];
    const float* adst0  = (const float*)d_in[5];
    const float* b0     = (const float*)d_in[6];
    const float* W1     = (const float*)d_in[7];
    const float* asrc1  = (const float*)d_in[8];
    const float* adst1  = (const float*)d_in[9];
    const float* b1     = (const float*)d_in[10];
    const float* W2     = (const float*)d_in[11];
    const float* asrc2  = (const float*)d_in[12];
    const float* adst2  = (const float*)d_in[13];
    const float* b2     = (const float*)d_in[14];
    const float* l1w    = (const float*)d_in[15];
    const float* l1b    = (const float*)d_in[16];
    const float* l2w    = (const float*)d_in[17];
    const float* l2b    = (const float*)d_in[18];
    float* out = (float*)d_out;

    const int* esrc = eidx;
    const int* edst = eidx + N_EDGES;

    // workspace layout
    float* OUT  = (float*)d_ws;                       // N*128 fp32 (agg output / gemm input)
    float* ALS  = OUT + (long)N_NODES * 128;          // N*4
    float* ALD  = ALS + N_NODES * 4;                  // N*4
    float* h3   = ALD + N_NODES * 4;                  // N*32 (layer-2 agg output)
    float* gsum = h3 + (long)N_NODES * 32;            // 64*32
    float* gcnt = gsum + NUM_GRAPHS * 32;             // 64
    int* counts = (int*)(gcnt + NUM_GRAPHS);          // N
    int* pos    = counts + N_NODES;                   // N
    int* offs   = pos + N_NODES;                      // N+1
    int* bsum   = offs + (N_NODES + 1);               // SCAN_BLOCKS
    int* bofs   = bsum + SCAN_BLOCKS;                 // SCAN_BLOCKS
    int* ssrc   = bofs + SCAN_BLOCKS;                 // E_TOT
    unsigned short* Hb  = (unsigned short*)(ssrc + E_TOT);  // N*128 bf16
    unsigned short* H2b = Hb + (long)N_NODES * 128;         // N*32 bf16

    // zero counts+pos (contiguous) and gsum+gcnt (contiguous)
    hipMemsetAsync(counts, 0, (size_t)(2 * N_NODES) * 4, stream);
    hipMemsetAsync(gsum, 0, (size_t)(NUM_GRAPHS * 32 + NUM_GRAPHS) * 4, stream);

    int eblocks = (E_TOT + 255) / 256;
    hist_kernel<<<eblocks, 256, 0, stream>>>(edst, counts);
    bsum_kernel<<<SCAN_BLOCKS, 256, 0, stream>>>(counts, bsum);
    bscan_kernel<<<1, 256, 0, stream>>>(bsum, bofs);
    boffs_kernel<<<SCAN_BLOCKS, 256, 0, stream>>>(counts, bofs, offs);
    scatter_kernel<<<eblocks, 256, 0, stream>>>(esrc, edst, offs, pos, ssrc);

    // layer 0: x @ W0 -> Hb (bf16), agg -> OUT (+b0, ELU)
    gemm128_attn<<<1250, 256, 0, stream>>>(x, W0, asrc0, adst0, Hb, ALS, ALD);
    agg128<<<10000, 256, 0, stream>>>(Hb, ALS, ALD, offs, ssrc, b0, OUT);

    // layer 1: OUT @ W1 -> Hb, agg -> OUT (in place: agg reads only Hb/ALS/ALD)
    gemm128_attn<<<1250, 256, 0, stream>>>(OUT, W1, asrc1, adst1, Hb, ALS, ALD);
    agg128<<<10000, 256, 0, stream>>>(Hb, ALS, ALD, offs, ssrc, b1, OUT);

    // layer 2: OUT @ W2 -> H2b (N,32 bf16), agg -> h3 (+b2, ELU)
    gemm32_attn<<<1250, 256, 0, stream>>>(OUT, W2, asrc2, adst2, H2b, ALS, ALD);
    agg32<<<5000, 256, 0, stream>>>(H2b, ALS, ALD, offs, ssrc, b2, h3);

    // pool + MLP
    pool_kernel<<<125, 256, 0, stream>>>(h3, batch, gsum, gcnt);
    mlp_kernel<<<1, 256, 0, stream>>>(gsum, gcnt, l1w, l1b, l2w, l2b, out);
}

// Round 5
// 359.476 us; speedup vs baseline: 2.1593x; 1.0335x over previous
//
#include <hip/hip_runtime.h>
#include <hip/hip_bf16.h>

#define N_NODES 40000
#define N_EDGES 640000
#define E_TOT   (N_EDGES + N_NODES)
#define NUM_GRAPHS 64
#define SCAN_BLOCKS 160
#define SCAN_CHUNK  250   // 160*250 = 40000

__device__ inline float bf2f(unsigned short u) {
    union { unsigned int i; float f; } v; v.i = ((unsigned int)u) << 16; return v.f;
}
__device__ inline unsigned short f2bf(float f) {
    union { float f; unsigned int i; } v; v.f = f;
    unsigned int r = v.i + 0x7FFF + ((v.i >> 16) & 1);
    return (unsigned short)(r >> 16);
}

// ---------------- CSR build ----------------

__global__ __launch_bounds__(256) void hist_kernel(const int* __restrict__ edst,
                                                   int* __restrict__ counts) {
    int e = blockIdx.x * 256 + threadIdx.x;
    if (e >= E_TOT) return;
    int d = (e < N_EDGES) ? edst[e] : (e - N_EDGES);
    atomicAdd(&counts[d], 1);
}

__global__ __launch_bounds__(256) void bsum_kernel(const int* __restrict__ counts,
                                                   int* __restrict__ bsum) {
    __shared__ int ws[4];
    int b = blockIdx.x, tid = threadIdx.x;
    int idx = b * SCAN_CHUNK + tid;
    int v = (tid < SCAN_CHUNK) ? counts[idx] : 0;
#pragma unroll
    for (int off = 32; off >= 1; off >>= 1) v += __shfl_down(v, off, 64);
    if ((tid & 63) == 0) ws[tid >> 6] = v;
    __syncthreads();
    if (tid == 0) bsum[b] = ws[0] + ws[1] + ws[2] + ws[3];
}

__global__ __launch_bounds__(256) void bscan_kernel(const int* __restrict__ bsum,
                                                    int* __restrict__ bofs) {
    __shared__ int s[256];
    int tid = threadIdx.x;
    int v = (tid < SCAN_BLOCKS) ? bsum[tid] : 0;
    s[tid] = v;
    __syncthreads();
    for (int off = 1; off < 256; off <<= 1) {
        int t = (tid >= off) ? s[tid - off] : 0;
        __syncthreads();
        s[tid] += t;
        __syncthreads();
    }
    if (tid < SCAN_BLOCKS) bofs[tid] = s[tid] - v;  // exclusive
}

__global__ __launch_bounds__(256) void boffs_kernel(const int* __restrict__ counts,
                                                    const int* __restrict__ bofs,
                                                    int* __restrict__ offs) {
    __shared__ int s[256];
    int b = blockIdx.x, tid = threadIdx.x;
    int idx = b * SCAN_CHUNK + tid;
    int v = (tid < SCAN_CHUNK) ? counts[idx] : 0;
    s[tid] = v;
    __syncthreads();
    for (int off = 1; off < 256; off <<= 1) {
        int t = (tid >= off) ? s[tid - off] : 0;
        __syncthreads();
        s[tid] += t;
        __syncthreads();
    }
    int incl = s[tid];
    int base = bofs[b];
    if (tid < SCAN_CHUNK) {
        offs[idx] = base + incl - v;
        if (idx == N_NODES - 1) offs[N_NODES] = base + incl;
    }
}

__global__ __launch_bounds__(256) void scatter_kernel(const int* __restrict__ esrc,
                                                      const int* __restrict__ edst,
                                                      const int* __restrict__ offs,
                                                      int* __restrict__ pos,
                                                      int* __restrict__ ssrc) {
    int e = blockIdx.x * 256 + threadIdx.x;
    if (e >= E_TOT) return;
    int d, s;
    if (e < N_EDGES) { d = edst[e]; s = esrc[e]; }
    else             { d = e - N_EDGES; s = d; }
    int idx = offs[d] + atomicAdd(&pos[d], 1);
    ssrc[idx] = s;
}

// ---------------- GEMM + attention scores ----------------
// h = X @ W (K=128, M=128). One wave -> 8 rows, lane -> 2 cols. k-unrolled x8.
__global__ __launch_bounds__(256) void gemm128_attn(const float* __restrict__ X,
                                                    const float* __restrict__ W,
                                                    const float* __restrict__ asrc,
                                                    const float* __restrict__ adst,
                                                    unsigned short* __restrict__ Hb,
                                                    float* __restrict__ ALS,
                                                    float* __restrict__ ALD) {
    int wave = threadIdx.x >> 6;
    int lane = threadIdx.x & 63;
    int r0 = (blockIdx.x * 4 + wave) * 8;
    r0 = __builtin_amdgcn_readfirstlane(r0);
    if (r0 >= N_NODES) return;
    int c = lane * 2;
    int head = lane >> 4;
    float acc[8][2];
#pragma unroll
    for (int i = 0; i < 8; ++i) { acc[i][0] = 0.f; acc[i][1] = 0.f; }
    const float* x0 = X + (long)r0 * 128;
    for (int k = 0; k < 128; k += 8) {
        float2 w[8];
#pragma unroll
        for (int u = 0; u < 8; ++u)
            w[u] = *(const float2*)(W + (k + u) * 128 + c);
#pragma unroll
        for (int i = 0; i < 8; ++i) {
            float4 xa = *(const float4*)(x0 + i * 128 + k);
            float4 xb = *(const float4*)(x0 + i * 128 + k + 4);
            acc[i][0] += xa.x * w[0].x; acc[i][1] += xa.x * w[0].y;
            acc[i][0] += xa.y * w[1].x; acc[i][1] += xa.y * w[1].y;
            acc[i][0] += xa.z * w[2].x; acc[i][1] += xa.z * w[2].y;
            acc[i][0] += xa.w * w[3].x; acc[i][1] += xa.w * w[3].y;
            acc[i][0] += xb.x * w[4].x; acc[i][1] += xb.x * w[4].y;
            acc[i][0] += xb.y * w[5].x; acc[i][1] += xb.y * w[5].y;
            acc[i][0] += xb.z * w[6].x; acc[i][1] += xb.z * w[6].y;
            acc[i][0] += xb.w * w[7].x; acc[i][1] += xb.w * w[7].y;
        }
    }
    float as0 = asrc[c], as1 = asrc[c + 1];
    float ad0 = adst[c], ad1 = adst[c + 1];
#pragma unroll
    for (int i = 0; i < 8; ++i) {
        int r = r0 + i;
        float h0 = acc[i][0], h1 = acc[i][1];
        ushort2 hb; hb.x = f2bf(h0); hb.y = f2bf(h1);
        *(ushort2*)(Hb + (long)r * 128 + c) = hb;
        float ps = h0 * as0 + h1 * as1;
        float pd = h0 * ad0 + h1 * ad1;
#pragma unroll
        for (int off = 8; off >= 1; off >>= 1) {
            ps += __shfl_xor(ps, off, 64);
            pd += __shfl_xor(pd, off, 64);
        }
        if ((lane & 15) == 0) {
            ALS[r * 4 + head] = ps;
            ALD[r * 4 + head] = pd;
        }
    }
}

// h2 = X @ W2 (K=128, M=32, 1 head). One wave -> 8 rows; both halves duplicate.
__global__ __launch_bounds__(256) void gemm32_attn(const float* __restrict__ X,
                                                   const float* __restrict__ W,
                                                   const float* __restrict__ asrc,
                                                   const float* __restrict__ adst,
                                                   unsigned short* __restrict__ H2b,
                                                   float* __restrict__ ALS,
                                                   float* __restrict__ ALD) {
    int wave = threadIdx.x >> 6;
    int lane = threadIdx.x & 63;
    int col = lane & 31;
    int r0 = (blockIdx.x * 4 + wave) * 8;
    r0 = __builtin_amdgcn_readfirstlane(r0);
    if (r0 >= N_NODES) return;
    float acc[8];
#pragma unroll
    for (int i = 0; i < 8; ++i) acc[i] = 0.f;
    const float* x0 = X + (long)r0 * 128;
    for (int k = 0; k < 128; k += 8) {
        float w[8];
#pragma unroll
        for (int u = 0; u < 8; ++u) w[u] = W[(k + u) * 32 + col];
#pragma unroll
        for (int i = 0; i < 8; ++i) {
            float4 xa = *(const float4*)(x0 + i * 128 + k);
            float4 xb = *(const float4*)(x0 + i * 128 + k + 4);
            acc[i] += xa.x * w[0]; acc[i] += xa.y * w[1];
            acc[i] += xa.z * w[2]; acc[i] += xa.w * w[3];
            acc[i] += xb.x * w[4]; acc[i] += xb.y * w[5];
            acc[i] += xb.z * w[6]; acc[i] += xb.w * w[7];
        }
    }
    float as = asrc[col], ad = adst[col];
#pragma unroll
    for (int i = 0; i < 8; ++i) {
        int r = r0 + i;
        float ps = acc[i] * as, pd = acc[i] * ad;
#pragma unroll
        for (int off = 16; off >= 1; off >>= 1) {
            ps += __shfl_xor(ps, off, 64);
            pd += __shfl_xor(pd, off, 64);
        }
        if (lane == 0) { ALS[r] = ps; ALD[r] = pd; }
        if (lane < 32) H2b[r * 32 + col] = f2bf(acc[i]);
    }
}

// ---------------- Edge aggregation, CSR by dst, batched-gather version ----------------
// One wave per node; lane -> 2 bf16 channels, head = lane>>4, edge slot = lane&15.
// Chunk of 16 edges: coalesced ssrc load + 16-wide parallel ALS float4 gather,
// broadcast (s,w) via width-16 shuffles, 16 independent H-row gathers in flight.
__global__ __launch_bounds__(256) void agg128(const unsigned short* __restrict__ Hb,
                                              const float* __restrict__ ALS,
                                              const float* __restrict__ ALD,
                                              const int* __restrict__ offs,
                                              const int* __restrict__ ssrc,
                                              const float* __restrict__ bias,
                                              float* __restrict__ OUT) {
    int n = blockIdx.x * 4 + (threadIdx.x >> 6);
    n = __builtin_amdgcn_readfirstlane(n);
    if (n >= N_NODES) return;
    int lane = threadIdx.x & 63;
    int c = lane * 2;
    int head = lane >> 4;
    int e16 = lane & 15;
    float aldh = ALD[n * 4 + head];
    int j0 = __builtin_amdgcn_readfirstlane(offs[n]);
    int j1 = __builtin_amdgcn_readfirstlane(offs[n + 1]);
    float a0 = 0.f, a1 = 0.f, dsum = 0.f;
    for (int jb = j0; jb < j1; jb += 16) {
        int j = jb + e16;
        int jc = (j < j1) ? j : (j1 - 1);
        int s = ssrc[jc];
        float4 als4 = *(const float4*)(ALS + (long)s * 4);
        float alsv = (head == 0) ? als4.x : (head == 1) ? als4.y
                   : (head == 2) ? als4.z : als4.w;
        float e = alsv + aldh;
        e = (e > 0.f) ? e : 0.2f * e;
        float w = (j < j1) ? __expf(e) : 0.f;
        int st[16]; float wt[16];
#pragma unroll
        for (int t = 0; t < 16; ++t) {
            st[t] = __shfl(s, t, 16);
            wt[t] = __shfl(w, t, 16);
        }
        unsigned int hv[16];
#pragma unroll
        for (int t = 0; t < 16; ++t)
            hv[t] = *(const unsigned int*)(Hb + (long)st[t] * 128 + c);
#pragma unroll
        for (int t = 0; t < 16; ++t) {
            float h0 = bf2f((unsigned short)(hv[t] & 0xFFFF));
            float h1 = bf2f((unsigned short)(hv[t] >> 16));
            dsum += wt[t];
            a0 += wt[t] * h0;
            a1 += wt[t] * h1;
        }
    }
    float inv = 1.0f / dsum;
    float o0 = a0 * inv + bias[c];
    float o1 = a1 * inv + bias[c + 1];
    o0 = (o0 > 0.f) ? o0 : (__expf(o0) - 1.f);
    o1 = (o1 > 0.f) ? o1 : (__expf(o1) - 1.f);
    *(float2*)(OUT + (long)n * 128 + c) = make_float2(o0, o1);
}

// 32-channel, 1-head; one wave = 2 nodes (half-wave each), 16-edge chunks.
__global__ __launch_bounds__(256) void agg32(const unsigned short* __restrict__ H2b,
                                             const float* __restrict__ ALS,
                                             const float* __restrict__ ALD,
                                             const int* __restrict__ offs,
                                             const int* __restrict__ ssrc,
                                             const float* __restrict__ bias,
                                             float* __restrict__ OUT) {
    int wv = blockIdx.x * 4 + (threadIdx.x >> 6);
    int lane = threadIdx.x & 63;
    int col = lane & 31;
    int half = lane >> 5;
    int e16 = lane & 15;
    int n = wv * 2 + half;
    if (n >= N_NODES) return;
    float aldn = ALD[n];
    int j0 = offs[n], j1 = offs[n + 1];
    float a = 0.f, dsum = 0.f;
    for (int jb = j0; jb < j1; jb += 16) {
        int j = jb + e16;
        int jc = (j < j1) ? j : (j1 - 1);
        int s = ssrc[jc];
        float e = ALS[s] + aldn;
        e = (e > 0.f) ? e : 0.2f * e;
        float w = (j < j1) ? __expf(e) : 0.f;
        int st[16]; float wt[16];
#pragma unroll
        for (int t = 0; t < 16; ++t) {
            st[t] = __shfl(s, t, 16);
            wt[t] = __shfl(w, t, 16);
        }
        unsigned short hv[16];
#pragma unroll
        for (int t = 0; t < 16; ++t)
            hv[t] = H2b[st[t] * 32 + col];
#pragma unroll
        for (int t = 0; t < 16; ++t) {
            dsum += wt[t];
            a += wt[t] * bf2f(hv[t]);
        }
    }
    float o = a / dsum + bias[col];
    o = (o > 0.f) ? o : (__expf(o) - 1.f);
    OUT[n * 32 + col] = o;
}

// ---------------- Pooling + MLP ----------------
__global__ __launch_bounds__(256) void pool_kernel(const float* __restrict__ H3,
                                                   const int* __restrict__ batch,
                                                   float* __restrict__ gsum,
                                                   float* __restrict__ gcnt) {
    const int CHUNK = 40;
    int gid = (blockIdx.x * 256 + threadIdx.x) >> 5;
    int c = threadIdx.x & 31;
    int n0 = gid * CHUNK;
    if (n0 >= N_NODES) return;
    int n1 = n0 + CHUNK;
    if (n1 > N_NODES) n1 = N_NODES;
    int cur = batch[n0];
    float acc = 0.f;
    int cnt = 0;
    for (int n = n0; n < n1; ++n) {
        int b = batch[n];
        if (b != cur) {
            atomicAdd(&gsum[cur * 32 + c], acc);
            if (c == 0) atomicAdd(&gcnt[cur], (float)cnt);
            cur = b; acc = 0.f; cnt = 0;
        }
        acc += H3[n * 32 + c];
        cnt++;
    }
    atomicAdd(&gsum[cur * 32 + c], acc);
    if (c == 0) atomicAdd(&gcnt[cur], (float)cnt);
}

__global__ __launch_bounds__(256) void mlp_kernel(const float* __restrict__ gsum,
                                                  const float* __restrict__ gcnt,
                                                  const float* __restrict__ l1w,
                                                  const float* __restrict__ l1b,
                                                  const float* __restrict__ l2w,
                                                  const float* __restrict__ l2b,
                                                  float* __restrict__ out) {
    __shared__ float g[NUM_GRAPHS * 32];
    __shared__ float t1[NUM_GRAPHS * 128];
    int tid = threadIdx.x;
    for (int i = tid; i < NUM_GRAPHS * 32; i += 256) {
        float c = gcnt[i >> 5];
        g[i] = gsum[i] / fmaxf(c, 1.0f);
    }
    __syncthreads();
    for (int i = tid; i < NUM_GRAPHS * 128; i += 256) {
        int r = i >> 7, j = i & 127;
        float a = l1b[j];
        for (int k = 0; k < 32; ++k) a += g[r * 32 + k] * l1w[k * 128 + j];
        t1[i] = fmaxf(a, 0.f);
    }
    __syncthreads();
    for (int i = tid; i < NUM_GRAPHS * 8; i += 256) {
        int r = i >> 3, j = i & 7;
        float a = l2b[j];
        for (int k = 0; k < 128; ++k) a += t1[r * 128 + k] * l2w[k * 8 + j];
        out[i] = a;
    }
}

// ---------------- host ----------------

extern "C" void kernel_launch(void* const* d_in, const int* in_sizes, int n_in,
                              void* d_out, int out_size, void* d_ws, size_t ws_size,
                              hipStream_t stream) {
    const float* x      = (const float*)d_in[0];
    const int*   eidx   = (const int*)d_in[1];
    const int*   batch  = (const int*)d_in[2];
    const float* W0     = (const float*)d_in[3];
    const float* asrc0  = (const float*)d_in[4];
    const float* adst0  = (const float*)d_in[5];
    const float* b0     = (const float*)d_in[6];
    const float* W1     = (const float*)d_in[7];
    const float* asrc1  = (const float*)d_in[8];
    const float* adst1  = (const float*)d_in[9];
    const float* b1     = (const float*)d_in[10];
    const float* W2     = (const float*)d_in[11];
    const float* asrc2  = (const float*)d_in[12];
    const float* adst2  = (const float*)d_in[13];
    const float* b2     = (const float*)d_in[14];
    const float* l1w    = (const float*)d_in[15];
    const float* l1b    = (const float*)d_in[16];
    const float* l2w    = (const float*)d_in[17];
    const float* l2b    = (const float*)d_in[18];
    float* out = (float*)d_out;

    const int* esrc = eidx;
    const int* edst = eidx + N_EDGES;

    // workspace layout
    float* OUT  = (float*)d_ws;                       // N*128 fp32 (agg output / gemm input)
    float* ALS  = OUT + (long)N_NODES * 128;          // N*4
    float* ALD  = ALS + N_NODES * 4;                  // N*4
    float* h3   = ALD + N_NODES * 4;                  // N*32 (layer-2 agg output)
    float* gsum = h3 + (long)N_NODES * 32;            // 64*32
    float* gcnt = gsum + NUM_GRAPHS * 32;             // 64
    int* counts = (int*)(gcnt + NUM_GRAPHS);          // N
    int* pos    = counts + N_NODES;                   // N
    int* offs   = pos + N_NODES;                      // N+1
    int* bsum   = offs + (N_NODES + 1);               // SCAN_BLOCKS
    int* bofs   = bsum + SCAN_BLOCKS;                 // SCAN_BLOCKS
    int* ssrc   = bofs + SCAN_BLOCKS;                 // E_TOT
    unsigned short* Hb  = (unsigned short*)(ssrc + E_TOT);  // N*128 bf16
    unsigned short* H2b = Hb + (long)N_NODES * 128;         // N*32 bf16

    hipMemsetAsync(counts, 0, (size_t)(2 * N_NODES) * 4, stream);
    hipMemsetAsync(gsum, 0, (size_t)(NUM_GRAPHS * 32 + NUM_GRAPHS) * 4, stream);

    int eblocks = (E_TOT + 255) / 256;
    hist_kernel<<<eblocks, 256, 0, stream>>>(edst, counts);
    bsum_kernel<<<SCAN_BLOCKS, 256, 0, stream>>>(counts, bsum);
    bscan_kernel<<<1, 256, 0, stream>>>(bsum, bofs);
    boffs_kernel<<<SCAN_BLOCKS, 256, 0, stream>>>(counts, bofs, offs);
    scatter_kernel<<<eblocks, 256, 0, stream>>>(esrc, edst, offs, pos, ssrc);

    // layer 0: x @ W0 -> Hb (bf16), agg -> OUT (+b0, ELU)
    gemm128_attn<<<1250, 256, 0, stream>>>(x, W0, asrc0, adst0, Hb, ALS, ALD);
    agg128<<<10000, 256, 0, stream>>>(Hb, ALS, ALD, offs, ssrc, b0, OUT);

    // layer 1: OUT @ W1 -> Hb, agg -> OUT
    gemm128_attn<<<1250, 256, 0, stream>>>(OUT, W1, asrc1, adst1, Hb, ALS, ALD);
    agg128<<<10000, 256, 0, stream>>>(Hb, ALS, ALD, offs, ssrc, b1, OUT);

    // layer 2: OUT @ W2 -> H2b (N,32 bf16), agg -> h3 (+b2, ELU)
    gemm32_attn<<<1250, 256, 0, stream>>>(OUT, W2, asrc2, adst2, H2b, ALS, ALD);
    agg32<<<5000, 256, 0, stream>>>(H2b, ALS, ALD, offs, ssrc, b2, h3);

    // pool + MLP
    pool_kernel<<<125, 256, 0, stream>>>(h3, batch, gsum, gcnt);
    mlp_kernel<<<1, 256, 0, stream>>>(gsum, gcnt, l1w, l1b, l2w, l2b, out);
}

// Round 6
// 354.495 us; speedup vs baseline: 2.1897x; 1.0140x over previous
//
#include <hip/hip_runtime.h>
#include <hip/hip_bf16.h>

#define N_NODES 40000
#define N_EDGES 640000
#define E_TOT   (N_EDGES + N_NODES)
#define NUM_GRAPHS 64
#define SCAN_BLOCKS 160
#define SCAN_CHUNK  250   // 160*250 = 40000

typedef __attribute__((ext_vector_type(8))) short bf16x8;
typedef __attribute__((ext_vector_type(4))) float f32x4;

__device__ inline float bf2f(unsigned short u) {
    union { unsigned int i; float f; } v; v.i = ((unsigned int)u) << 16; return v.f;
}
__device__ inline unsigned short f2bf(float f) {
    union { float f; unsigned int i; } v; v.f = f;
    unsigned int r = v.i + 0x7FFF + ((v.i >> 16) & 1);
    return (unsigned short)(r >> 16);
}

// ---------------- conversions ----------------

__global__ __launch_bounds__(256) void cvt_x(const float* __restrict__ x,
                                             unsigned short* __restrict__ xb) {
    int i = blockIdx.x * 256 + threadIdx.x;   // over float4s: N*128/4 = 1.28M
    float4 v = ((const float4*)x)[i];
    ushort4 o;
    o.x = f2bf(v.x); o.y = f2bf(v.y); o.z = f2bf(v.z); o.w = f2bf(v.w);
    ((ushort4*)xb)[i] = o;
}

// Wt[n*128+k] = bf16(W[k*128+n])  (transpose so B-frags are k-contiguous)
__global__ __launch_bounds__(256) void cvt_wt(const float* __restrict__ W,
                                              unsigned short* __restrict__ Wt) {
    int idx = blockIdx.x * 256 + threadIdx.x;   // 16384
    int n = idx >> 7, k = idx & 127;
    Wt[idx] = f2bf(W[k * 128 + n]);
}

// ---------------- CSR build ----------------

__global__ __launch_bounds__(256) void hist_kernel(const int* __restrict__ edst,
                                                   int* __restrict__ counts) {
    int e = blockIdx.x * 256 + threadIdx.x;
    if (e >= E_TOT) return;
    int d = (e < N_EDGES) ? edst[e] : (e - N_EDGES);
    atomicAdd(&counts[d], 1);
}

__global__ __launch_bounds__(256) void bsum_kernel(const int* __restrict__ counts,
                                                   int* __restrict__ bsum) {
    __shared__ int ws[4];
    int b = blockIdx.x, tid = threadIdx.x;
    int idx = b * SCAN_CHUNK + tid;
    int v = (tid < SCAN_CHUNK) ? counts[idx] : 0;
#pragma unroll
    for (int off = 32; off >= 1; off >>= 1) v += __shfl_down(v, off, 64);
    if ((tid & 63) == 0) ws[tid >> 6] = v;
    __syncthreads();
    if (tid == 0) bsum[b] = ws[0] + ws[1] + ws[2] + ws[3];
}

__global__ __launch_bounds__(256) void bscan_kernel(const int* __restrict__ bsum,
                                                    int* __restrict__ bofs) {
    __shared__ int s[256];
    int tid = threadIdx.x;
    int v = (tid < SCAN_BLOCKS) ? bsum[tid] : 0;
    s[tid] = v;
    __syncthreads();
    for (int off = 1; off < 256; off <<= 1) {
        int t = (tid >= off) ? s[tid - off] : 0;
        __syncthreads();
        s[tid] += t;
        __syncthreads();
    }
    if (tid < SCAN_BLOCKS) bofs[tid] = s[tid] - v;  // exclusive
}

__global__ __launch_bounds__(256) void boffs_kernel(const int* __restrict__ counts,
                                                    const int* __restrict__ bofs,
                                                    int* __restrict__ offs) {
    __shared__ int s[256];
    int b = blockIdx.x, tid = threadIdx.x;
    int idx = b * SCAN_CHUNK + tid;
    int v = (tid < SCAN_CHUNK) ? counts[idx] : 0;
    s[tid] = v;
    __syncthreads();
    for (int off = 1; off < 256; off <<= 1) {
        int t = (tid >= off) ? s[tid - off] : 0;
        __syncthreads();
        s[tid] += t;
        __syncthreads();
    }
    int incl = s[tid];
    int base = bofs[b];
    if (tid < SCAN_CHUNK) {
        offs[idx] = base + incl - v;
        if (idx == N_NODES - 1) offs[N_NODES] = base + incl;
    }
}

__global__ __launch_bounds__(256) void scatter_kernel(const int* __restrict__ esrc,
                                                      const int* __restrict__ edst,
                                                      const int* __restrict__ offs,
                                                      int* __restrict__ pos,
                                                      int* __restrict__ ssrc) {
    int e = blockIdx.x * 256 + threadIdx.x;
    if (e >= E_TOT) return;
    int d, s;
    if (e < N_EDGES) { d = edst[e]; s = esrc[e]; }
    else             { d = e - N_EDGES; s = d; }
    int idx = offs[d] + atomicAdd(&pos[d], 1);
    ssrc[idx] = s;
}

// ---------------- MFMA GEMM + attention scores (128 -> 128) ----------------
// One wave -> 16 rows x 128 cols. A = Xb rows (bf16), B = Wt (n-major bf16).
// C/D layout: col = lane&15, row = quad*4 + reg (m89-verified).
__global__ __launch_bounds__(256) void gemm128_mfma(const unsigned short* __restrict__ Xb,
                                                    const unsigned short* __restrict__ Wt,
                                                    const float* __restrict__ asrc,
                                                    const float* __restrict__ adst,
                                                    unsigned short* __restrict__ Hb,
                                                    float* __restrict__ ALS,
                                                    float* __restrict__ ALD) {
    int wave = threadIdx.x >> 6;
    int lane = threadIdx.x & 63;
    int l15 = lane & 15;
    int q = lane >> 4;
    int r0 = (blockIdx.x * 4 + wave) * 16;   // grid exact: 625*4*16 = 40000

    f32x4 acc[8];
#pragma unroll
    for (int t = 0; t < 8; ++t) acc[t] = (f32x4){0.f, 0.f, 0.f, 0.f};

    float asv[8], adv[8];
#pragma unroll
    for (int t = 0; t < 8; ++t) {
        int c = t * 16 + l15;
        asv[t] = asrc[c];
        adv[t] = adst[c];
    }

    const unsigned short* xrow = Xb + (long)(r0 + l15) * 128 + q * 8;
    const unsigned short* wrow = Wt + (long)l15 * 128 + q * 8;
#pragma unroll
    for (int kt = 0; kt < 4; ++kt) {
        bf16x8 a = *(const bf16x8*)(xrow + kt * 32);
#pragma unroll
        for (int t = 0; t < 8; ++t) {
            bf16x8 b = *(const bf16x8*)(wrow + (long)t * 16 * 128 + kt * 32);
            acc[t] = __builtin_amdgcn_mfma_f32_16x16x32_bf16(a, b, acc[t], 0, 0, 0);
        }
    }

    // H (bf16) write: lane holds rows q*4+i, col t*16+l15
#pragma unroll
    for (int t = 0; t < 8; ++t)
#pragma unroll
        for (int i = 0; i < 4; ++i)
            Hb[(long)(r0 + q * 4 + i) * 128 + t * 16 + l15] = f2bf(acc[t][i]);

    // attention scores: als[r][h] = sum_c h[r][c]*asrc[c], head h = c>>5
#pragma unroll
    for (int i = 0; i < 4; ++i) {
        float ps0 = acc[0][i] * asv[0] + acc[1][i] * asv[1];
        float ps1 = acc[2][i] * asv[2] + acc[3][i] * asv[3];
        float ps2 = acc[4][i] * asv[4] + acc[5][i] * asv[5];
        float ps3 = acc[6][i] * asv[6] + acc[7][i] * asv[7];
        float pd0 = acc[0][i] * adv[0] + acc[1][i] * adv[1];
        float pd1 = acc[2][i] * adv[2] + acc[3][i] * adv[3];
        float pd2 = acc[4][i] * adv[4] + acc[5][i] * adv[5];
        float pd3 = acc[6][i] * adv[6] + acc[7][i] * adv[7];
#pragma unroll
        for (int m = 1; m < 16; m <<= 1) {
            ps0 += __shfl_xor(ps0, m, 16); ps1 += __shfl_xor(ps1, m, 16);
            ps2 += __shfl_xor(ps2, m, 16); ps3 += __shfl_xor(ps3, m, 16);
            pd0 += __shfl_xor(pd0, m, 16); pd1 += __shfl_xor(pd1, m, 16);
            pd2 += __shfl_xor(pd2, m, 16); pd3 += __shfl_xor(pd3, m, 16);
        }
        if (l15 == 0) {
            int r = r0 + q * 4 + i;
            *(float4*)(ALS + (long)r * 4) = make_float4(ps0, ps1, ps2, ps3);
            *(float4*)(ALD + (long)r * 4) = make_float4(pd0, pd1, pd2, pd3);
        }
    }
}

// h2 = Xb @ W2 (K=128 bf16 in, M=32, 1 head, fp32 W). One wave -> 8 rows.
__global__ __launch_bounds__(256) void gemm32_attn(const unsigned short* __restrict__ Xb,
                                                   const float* __restrict__ W,
                                                   const float* __restrict__ asrc,
                                                   const float* __restrict__ adst,
                                                   unsigned short* __restrict__ H2b,
                                                   float* __restrict__ ALS,
                                                   float* __restrict__ ALD) {
    int wave = threadIdx.x >> 6;
    int lane = threadIdx.x & 63;
    int col = lane & 31;
    int r0 = (blockIdx.x * 4 + wave) * 8;
    r0 = __builtin_amdgcn_readfirstlane(r0);
    if (r0 >= N_NODES) return;
    float acc[8];
#pragma unroll
    for (int i = 0; i < 8; ++i) acc[i] = 0.f;
    const unsigned short* x0 = Xb + (long)r0 * 128;
    for (int k = 0; k < 128; k += 8) {
        float w[8];
#pragma unroll
        for (int u = 0; u < 8; ++u) w[u] = W[(k + u) * 32 + col];
#pragma unroll
        for (int i = 0; i < 8; ++i) {
            uint4 xa = *(const uint4*)(x0 + i * 128 + k);   // 8 bf16
            acc[i] += bf2f((unsigned short)(xa.x & 0xFFFF)) * w[0];
            acc[i] += bf2f((unsigned short)(xa.x >> 16)) * w[1];
            acc[i] += bf2f((unsigned short)(xa.y & 0xFFFF)) * w[2];
            acc[i] += bf2f((unsigned short)(xa.y >> 16)) * w[3];
            acc[i] += bf2f((unsigned short)(xa.z & 0xFFFF)) * w[4];
            acc[i] += bf2f((unsigned short)(xa.z >> 16)) * w[5];
            acc[i] += bf2f((unsigned short)(xa.w & 0xFFFF)) * w[6];
            acc[i] += bf2f((unsigned short)(xa.w >> 16)) * w[7];
        }
    }
    float as = asrc[col], ad = adst[col];
#pragma unroll
    for (int i = 0; i < 8; ++i) {
        int r = r0 + i;
        float ps = acc[i] * as, pd = acc[i] * ad;
#pragma unroll
        for (int off = 16; off >= 1; off >>= 1) {
            ps += __shfl_xor(ps, off, 64);
            pd += __shfl_xor(pd, off, 64);
        }
        if (lane == 0) { ALS[r] = ps; ALD[r] = pd; }
        if (lane < 32) H2b[r * 32 + col] = f2bf(acc[i]);
    }
}

// ---------------- Edge aggregation, CSR by dst, batched-gather ----------------
// One wave per node; lane -> 2 bf16 channels, head = lane>>4, edge slot = lane&15.
// Output written bf16 (consumer is the next GEMM).
__global__ __launch_bounds__(256) void agg128(const unsigned short* __restrict__ Hb,
                                              const float* __restrict__ ALS,
                                              const float* __restrict__ ALD,
                                              const int* __restrict__ offs,
                                              const int* __restrict__ ssrc,
                                              const float* __restrict__ bias,
                                              unsigned short* __restrict__ OUTb) {
    int n = blockIdx.x * 4 + (threadIdx.x >> 6);
    n = __builtin_amdgcn_readfirstlane(n);
    if (n >= N_NODES) return;
    int lane = threadIdx.x & 63;
    int c = lane * 2;
    int head = lane >> 4;
    int e16 = lane & 15;
    float aldh = ALD[n * 4 + head];
    int j0 = __builtin_amdgcn_readfirstlane(offs[n]);
    int j1 = __builtin_amdgcn_readfirstlane(offs[n + 1]);
    float a0 = 0.f, a1 = 0.f, dsum = 0.f;
    for (int jb = j0; jb < j1; jb += 16) {
        int j = jb + e16;
        int jc = (j < j1) ? j : (j1 - 1);
        int s = ssrc[jc];
        float4 als4 = *(const float4*)(ALS + (long)s * 4);
        float alsv = (head == 0) ? als4.x : (head == 1) ? als4.y
                   : (head == 2) ? als4.z : als4.w;
        float e = alsv + aldh;
        e = (e > 0.f) ? e : 0.2f * e;
        float w = (j < j1) ? __expf(e) : 0.f;
        int st[16]; float wt[16];
#pragma unroll
        for (int t = 0; t < 16; ++t) {
            st[t] = __shfl(s, t, 16);
            wt[t] = __shfl(w, t, 16);
        }
        unsigned int hv[16];
#pragma unroll
        for (int t = 0; t < 16; ++t)
            hv[t] = *(const unsigned int*)(Hb + (long)st[t] * 128 + c);
#pragma unroll
        for (int t = 0; t < 16; ++t) {
            float h0 = bf2f((unsigned short)(hv[t] & 0xFFFF));
            float h1 = bf2f((unsigned short)(hv[t] >> 16));
            dsum += wt[t];
            a0 += wt[t] * h0;
            a1 += wt[t] * h1;
        }
    }
    float inv = 1.0f / dsum;
    float o0 = a0 * inv + bias[c];
    float o1 = a1 * inv + bias[c + 1];
    o0 = (o0 > 0.f) ? o0 : (__expf(o0) - 1.f);
    o1 = (o1 > 0.f) ? o1 : (__expf(o1) - 1.f);
    ushort2 ob; ob.x = f2bf(o0); ob.y = f2bf(o1);
    *(ushort2*)(OUTb + (long)n * 128 + c) = ob;
}

// 32-channel, 1-head; one wave = 2 nodes (half-wave each), 16-edge chunks.
__global__ __launch_bounds__(256) void agg32(const unsigned short* __restrict__ H2b,
                                             const float* __restrict__ ALS,
                                             const float* __restrict__ ALD,
                                             const int* __restrict__ offs,
                                             const int* __restrict__ ssrc,
                                             const float* __restrict__ bias,
                                             float* __restrict__ OUT) {
    int wv = blockIdx.x * 4 + (threadIdx.x >> 6);
    int lane = threadIdx.x & 63;
    int col = lane & 31;
    int half = lane >> 5;
    int e16 = lane & 15;
    int n = wv * 2 + half;
    if (n >= N_NODES) return;
    float aldn = ALD[n];
    int j0 = offs[n], j1 = offs[n + 1];
    float a = 0.f, dsum = 0.f;
    for (int jb = j0; jb < j1; jb += 16) {
        int j = jb + e16;
        int jc = (j < j1) ? j : (j1 - 1);
        int s = ssrc[jc];
        float e = ALS[s] + aldn;
        e = (e > 0.f) ? e : 0.2f * e;
        float w = (j < j1) ? __expf(e) : 0.f;
        int st[16]; float wt[16];
#pragma unroll
        for (int t = 0; t < 16; ++t) {
            st[t] = __shfl(s, t, 16);
            wt[t] = __shfl(w, t, 16);
        }
        unsigned short hv[16];
#pragma unroll
        for (int t = 0; t < 16; ++t)
            hv[t] = H2b[st[t] * 32 + col];
#pragma unroll
        for (int t = 0; t < 16; ++t) {
            dsum += wt[t];
            a += wt[t] * bf2f(hv[t]);
        }
    }
    float o = a / dsum + bias[col];
    o = (o > 0.f) ? o : (__expf(o) - 1.f);
    OUT[n * 32 + col] = o;
}

// ---------------- Pooling + MLP ----------------
__global__ __launch_bounds__(256) void pool_kernel(const float* __restrict__ H3,
                                                   const int* __restrict__ batch,
                                                   float* __restrict__ gsum,
                                                   float* __restrict__ gcnt) {
    const int CHUNK = 40;
    int gid = (blockIdx.x * 256 + threadIdx.x) >> 5;
    int c = threadIdx.x & 31;
    int n0 = gid * CHUNK;
    if (n0 >= N_NODES) return;
    int n1 = n0 + CHUNK;
    if (n1 > N_NODES) n1 = N_NODES;
    int cur = batch[n0];
    float acc = 0.f;
    int cnt = 0;
    for (int n = n0; n < n1; ++n) {
        int b = batch[n];
        if (b != cur) {
            atomicAdd(&gsum[cur * 32 + c], acc);
            if (c == 0) atomicAdd(&gcnt[cur], (float)cnt);
            cur = b; acc = 0.f; cnt = 0;
        }
        acc += H3[n * 32 + c];
        cnt++;
    }
    atomicAdd(&gsum[cur * 32 + c], acc);
    if (c == 0) atomicAdd(&gcnt[cur], (float)cnt);
}

__global__ __launch_bounds__(256) void mlp_kernel(const float* __restrict__ gsum,
                                                  const float* __restrict__ gcnt,
                                                  const float* __restrict__ l1w,
                                                  const float* __restrict__ l1b,
                                                  const float* __restrict__ l2w,
                                                  const float* __restrict__ l2b,
                                                  float* __restrict__ out) {
    __shared__ float g[NUM_GRAPHS * 32];
    __shared__ float t1[NUM_GRAPHS * 128];
    int tid = threadIdx.x;
    for (int i = tid; i < NUM_GRAPHS * 32; i += 256) {
        float c = gcnt[i >> 5];
        g[i] = gsum[i] / fmaxf(c, 1.0f);
    }
    __syncthreads();
    for (int i = tid; i < NUM_GRAPHS * 128; i += 256) {
        int r = i >> 7, j = i & 127;
        float a = l1b[j];
        for (int k = 0; k < 32; ++k) a += g[r * 32 + k] * l1w[k * 128 + j];
        t1[i] = fmaxf(a, 0.f);
    }
    __syncthreads();
    for (int i = tid; i < NUM_GRAPHS * 8; i += 256) {
        int r = i >> 3, j = i & 7;
        float a = l2b[j];
        for (int k = 0; k < 128; ++k) a += t1[r * 128 + k] * l2w[k * 8 + j];
        out[i] = a;
    }
}

// ---------------- host ----------------

extern "C" void kernel_launch(void* const* d_in, const int* in_sizes, int n_in,
                              void* d_out, int out_size, void* d_ws, size_t ws_size,
                              hipStream_t stream) {
    const float* x      = (const float*)d_in[0];
    const int*   eidx   = (const int*)d_in[1];
    const int*   batch  = (const int*)d_in[2];
    const float* W0     = (const float*)d_in[3];
    const float* asrc0  = (const float*)d_in[4];
    const float* adst0  = (const float*)d_in[5];
    const float* b0     = (const float*)d_in[6];
    const float* W1     = (const float*)d_in[7];
    const float* asrc1  = (const float*)d_in[8];
    const float* adst1  = (const float*)d_in[9];
    const float* b1     = (const float*)d_in[10];
    const float* W2     = (const float*)d_in[11];
    const float* asrc2  = (const float*)d_in[12];
    const float* adst2  = (const float*)d_in[13];
    const float* b2     = (const float*)d_in[14];
    const float* l1w    = (const float*)d_in[15];
    const float* l1b    = (const float*)d_in[16];
    const float* l2w    = (const float*)d_in[17];
    const float* l2b    = (const float*)d_in[18];
    float* out = (float*)d_out;

    const int* esrc = eidx;
    const int* edst = eidx + N_EDGES;

    // workspace layout (fp32 region first for 16B-aligned float4 access)
    float* ALS  = (float*)d_ws;                       // N*4
    float* ALD  = ALS + N_NODES * 4;                  // N*4
    float* h3   = ALD + N_NODES * 4;                  // N*32
    float* gsum = h3 + (long)N_NODES * 32;            // 64*32
    float* gcnt = gsum + NUM_GRAPHS * 32;             // 64
    int* counts = (int*)(gcnt + NUM_GRAPHS);          // N
    int* pos    = counts + N_NODES;                   // N
    int* offs   = pos + N_NODES;                      // N+1
    int* bsum   = offs + (N_NODES + 1);               // SCAN_BLOCKS
    int* bofs   = bsum + SCAN_BLOCKS;                 // SCAN_BLOCKS
    int* ssrc   = bofs + SCAN_BLOCKS;                 // E_TOT
    int* ipad   = ssrc + E_TOT;                       // +1 pad for alignment
    unsigned short* Xb   = (unsigned short*)(ipad + 1);     // N*128 bf16
    unsigned short* Hb   = Xb + (long)N_NODES * 128;        // N*128 bf16
    unsigned short* OUTb = Hb + (long)N_NODES * 128;        // N*128 bf16
    unsigned short* H2b  = OUTb + (long)N_NODES * 128;      // N*32 bf16
    unsigned short* Wt0  = H2b + (long)N_NODES * 32;        // 128*128 bf16
    unsigned short* Wt1  = Wt0 + 128 * 128;                 // 128*128 bf16

    hipMemsetAsync(counts, 0, (size_t)(2 * N_NODES) * 4, stream);
    hipMemsetAsync(gsum, 0, (size_t)(NUM_GRAPHS * 32 + NUM_GRAPHS) * 4, stream);

    // conversions (independent of CSR)
    cvt_x<<<5000, 256, 0, stream>>>(x, Xb);
    cvt_wt<<<64, 256, 0, stream>>>(W0, Wt0);
    cvt_wt<<<64, 256, 0, stream>>>(W1, Wt1);

    int eblocks = (E_TOT + 255) / 256;
    hist_kernel<<<eblocks, 256, 0, stream>>>(edst, counts);
    bsum_kernel<<<SCAN_BLOCKS, 256, 0, stream>>>(counts, bsum);
    bscan_kernel<<<1, 256, 0, stream>>>(bsum, bofs);
    boffs_kernel<<<SCAN_BLOCKS, 256, 0, stream>>>(counts, bofs, offs);
    scatter_kernel<<<eblocks, 256, 0, stream>>>(esrc, edst, offs, pos, ssrc);

    // layer 0
    gemm128_mfma<<<625, 256, 0, stream>>>(Xb, Wt0, asrc0, adst0, Hb, ALS, ALD);
    agg128<<<10000, 256, 0, stream>>>(Hb, ALS, ALD, offs, ssrc, b0, OUTb);

    // layer 1
    gemm128_mfma<<<625, 256, 0, stream>>>(OUTb, Wt1, asrc1, adst1, Hb, ALS, ALD);
    agg128<<<10000, 256, 0, stream>>>(Hb, ALS, ALD, offs, ssrc, b1, OUTb);

    // layer 2
    gemm32_attn<<<1250, 256, 0, stream>>>(OUTb, W2, asrc2, adst2, H2b, ALS, ALD);
    agg32<<<5000, 256, 0, stream>>>(H2b, ALS, ALD, offs, ssrc, b2, h3);

    // pool + MLP
    pool_kernel<<<125, 256, 0, stream>>>(h3, batch, gsum, gcnt);
    mlp_kernel<<<1, 256, 0, stream>>>(gsum, gcnt, l1w, l1b, l2w, l2b, out);
}

// Round 7
// 342.432 us; speedup vs baseline: 2.2668x; 1.0352x over previous
//
#include <hip/hip_runtime.h>
#include <hip/hip_bf16.h>

#define N_NODES 40000
#define N_EDGES 640000
#define E_TOT   (N_EDGES + N_NODES)
#define NUM_GRAPHS 64
#define SCAN_BLOCKS 160
#define SCAN_CHUNK  250   // 160*250 = 40000
#define EQ4 (E_TOT / 4)   // 170000: edges per ILP-4 stride

typedef __attribute__((ext_vector_type(8))) short bf16x8;
typedef __attribute__((ext_vector_type(4))) float f32x4;

__device__ inline float bf2f(unsigned short u) {
    union { unsigned int i; float f; } v; v.i = ((unsigned int)u) << 16; return v.f;
}
__device__ inline unsigned short f2bf(float f) {
    union { float f; unsigned int i; } v; v.f = f;
    unsigned int r = v.i + 0x7FFF + ((v.i >> 16) & 1);
    return (unsigned short)(r >> 16);
}

// ---------------- conversions ----------------

__global__ __launch_bounds__(256) void cvt_x(const float* __restrict__ x,
                                             unsigned short* __restrict__ xb) {
    int i = blockIdx.x * 256 + threadIdx.x;   // over float4s: N*128/4 = 1.28M
    float4 v = ((const float4*)x)[i];
    ushort4 o;
    o.x = f2bf(v.x); o.y = f2bf(v.y); o.z = f2bf(v.z); o.w = f2bf(v.w);
    ((ushort4*)xb)[i] = o;
}

// Wt[n*K+k] = bf16(W[k*N+n]) for W0 (128x128), W1 (128x128), W2 (128x32)
__global__ __launch_bounds__(256) void cvt_w(const float* __restrict__ W0,
                                             const float* __restrict__ W1,
                                             const float* __restrict__ W2,
                                             unsigned short* __restrict__ Wt0,
                                             unsigned short* __restrict__ Wt1,
                                             unsigned short* __restrict__ Wt2) {
    int idx = blockIdx.x * 256 + threadIdx.x;   // 36864 total, grid 144
    if (idx < 16384) {
        int n = idx >> 7, k = idx & 127;
        Wt0[idx] = f2bf(W0[k * 128 + n]);
    } else if (idx < 32768) {
        int i = idx - 16384;
        int n = i >> 7, k = i & 127;
        Wt1[i] = f2bf(W1[k * 128 + n]);
    } else if (idx < 36864) {
        int i = idx - 32768;
        int n = i >> 7, k = i & 127;   // n in [0,32)
        Wt2[i] = f2bf(W2[k * 32 + n]);
    }
}

// ---------------- CSR build ----------------

// ILP-4: each thread handles 4 strided edges (independent atomics in flight)
__global__ __launch_bounds__(256) void hist_kernel(const int* __restrict__ edst,
                                                   int* __restrict__ counts) {
    int i = blockIdx.x * 256 + threadIdx.x;
    if (i >= EQ4) return;
#pragma unroll
    for (int u = 0; u < 4; ++u) {
        int e = i + u * EQ4;
        int d = (e < N_EDGES) ? edst[e] : (e - N_EDGES);
        atomicAdd(&counts[d], 1);
    }
}

__global__ __launch_bounds__(256) void bsum_kernel(const int* __restrict__ counts,
                                                   int* __restrict__ bsum) {
    __shared__ int ws[4];
    int b = blockIdx.x, tid = threadIdx.x;
    int idx = b * SCAN_CHUNK + tid;
    int v = (tid < SCAN_CHUNK) ? counts[idx] : 0;
#pragma unroll
    for (int off = 32; off >= 1; off >>= 1) v += __shfl_down(v, off, 64);
    if ((tid & 63) == 0) ws[tid >> 6] = v;
    __syncthreads();
    if (tid == 0) bsum[b] = ws[0] + ws[1] + ws[2] + ws[3];
}

__global__ __launch_bounds__(256) void bscan_kernel(const int* __restrict__ bsum,
                                                    int* __restrict__ bofs) {
    __shared__ int s[256];
    int tid = threadIdx.x;
    int v = (tid < SCAN_BLOCKS) ? bsum[tid] : 0;
    s[tid] = v;
    __syncthreads();
    for (int off = 1; off < 256; off <<= 1) {
        int t = (tid >= off) ? s[tid - off] : 0;
        __syncthreads();
        s[tid] += t;
        __syncthreads();
    }
    if (tid < SCAN_BLOCKS) bofs[tid] = s[tid] - v;  // exclusive
}

__global__ __launch_bounds__(256) void boffs_kernel(const int* __restrict__ counts,
                                                    const int* __restrict__ bofs,
                                                    int* __restrict__ offs) {
    __shared__ int s[256];
    int b = blockIdx.x, tid = threadIdx.x;
    int idx = b * SCAN_CHUNK + tid;
    int v = (tid < SCAN_CHUNK) ? counts[idx] : 0;
    s[tid] = v;
    __syncthreads();
    for (int off = 1; off < 256; off <<= 1) {
        int t = (tid >= off) ? s[tid - off] : 0;
        __syncthreads();
        s[tid] += t;
        __syncthreads();
    }
    int incl = s[tid];
    int base = bofs[b];
    if (tid < SCAN_CHUNK) {
        offs[idx] = base + incl - v;
        if (idx == N_NODES - 1) offs[N_NODES] = base + incl;
    }
}

// ILP-4: 4 independent (offs load -> atomicAdd -> store) chains per thread
__global__ __launch_bounds__(256) void scatter_kernel(const int* __restrict__ esrc,
                                                      const int* __restrict__ edst,
                                                      const int* __restrict__ offs,
                                                      int* __restrict__ pos,
                                                      int* __restrict__ ssrc) {
    int i = blockIdx.x * 256 + threadIdx.x;
    if (i >= EQ4) return;
    int d[4], s[4];
#pragma unroll
    for (int u = 0; u < 4; ++u) {
        int e = i + u * EQ4;
        if (e < N_EDGES) { d[u] = edst[e]; s[u] = esrc[e]; }
        else             { d[u] = e - N_EDGES; s[u] = d[u]; }
    }
    int base[4], rk[4];
#pragma unroll
    for (int u = 0; u < 4; ++u) base[u] = offs[d[u]];
#pragma unroll
    for (int u = 0; u < 4; ++u) rk[u] = atomicAdd(&pos[d[u]], 1);
#pragma unroll
    for (int u = 0; u < 4; ++u) ssrc[base[u] + rk[u]] = s[u];
}

// ---------------- MFMA GEMM + attention scores (128 -> 128) ----------------
// One wave -> 16 rows x 128 cols. C/D layout: col = lane&15, row = quad*4+reg.
__global__ __launch_bounds__(256) void gemm128_mfma(const unsigned short* __restrict__ Xb,
                                                    const unsigned short* __restrict__ Wt,
                                                    const float* __restrict__ asrc,
                                                    const float* __restrict__ adst,
                                                    unsigned short* __restrict__ Hb,
                                                    float* __restrict__ ALS,
                                                    float* __restrict__ ALD) {
    int wave = threadIdx.x >> 6;
    int lane = threadIdx.x & 63;
    int l15 = lane & 15;
    int q = lane >> 4;
    int r0 = (blockIdx.x * 4 + wave) * 16;   // 625*4*16 = 40000 exact

    f32x4 acc[8];
#pragma unroll
    for (int t = 0; t < 8; ++t) acc[t] = (f32x4){0.f, 0.f, 0.f, 0.f};

    float asv[8], adv[8];
#pragma unroll
    for (int t = 0; t < 8; ++t) {
        int c = t * 16 + l15;
        asv[t] = asrc[c];
        adv[t] = adst[c];
    }

    const unsigned short* xrow = Xb + (long)(r0 + l15) * 128 + q * 8;
    const unsigned short* wrow = Wt + (long)l15 * 128 + q * 8;
#pragma unroll
    for (int kt = 0; kt < 4; ++kt) {
        bf16x8 a = *(const bf16x8*)(xrow + kt * 32);
#pragma unroll
        for (int t = 0; t < 8; ++t) {
            bf16x8 b = *(const bf16x8*)(wrow + (long)t * 16 * 128 + kt * 32);
            acc[t] = __builtin_amdgcn_mfma_f32_16x16x32_bf16(a, b, acc[t], 0, 0, 0);
        }
    }

#pragma unroll
    for (int t = 0; t < 8; ++t)
#pragma unroll
        for (int i = 0; i < 4; ++i)
            Hb[(long)(r0 + q * 4 + i) * 128 + t * 16 + l15] = f2bf(acc[t][i]);

#pragma unroll
    for (int i = 0; i < 4; ++i) {
        float ps0 = acc[0][i] * asv[0] + acc[1][i] * asv[1];
        float ps1 = acc[2][i] * asv[2] + acc[3][i] * asv[3];
        float ps2 = acc[4][i] * asv[4] + acc[5][i] * asv[5];
        float ps3 = acc[6][i] * asv[6] + acc[7][i] * asv[7];
        float pd0 = acc[0][i] * adv[0] + acc[1][i] * adv[1];
        float pd1 = acc[2][i] * adv[2] + acc[3][i] * adv[3];
        float pd2 = acc[4][i] * adv[4] + acc[5][i] * adv[5];
        float pd3 = acc[6][i] * adv[6] + acc[7][i] * adv[7];
#pragma unroll
        for (int m = 1; m < 16; m <<= 1) {
            ps0 += __shfl_xor(ps0, m, 16); ps1 += __shfl_xor(ps1, m, 16);
            ps2 += __shfl_xor(ps2, m, 16); ps3 += __shfl_xor(ps3, m, 16);
            pd0 += __shfl_xor(pd0, m, 16); pd1 += __shfl_xor(pd1, m, 16);
            pd2 += __shfl_xor(pd2, m, 16); pd3 += __shfl_xor(pd3, m, 16);
        }
        if (l15 == 0) {
            int r = r0 + q * 4 + i;
            *(float4*)(ALS + (long)r * 4) = make_float4(ps0, ps1, ps2, ps3);
            *(float4*)(ALD + (long)r * 4) = make_float4(pd0, pd1, pd2, pd3);
        }
    }
}

// ---------------- MFMA GEMM (128 -> 32, 1 head) ----------------
// One wave -> 16 rows x 32 cols (2 col-tiles x 4 K-steps).
__global__ __launch_bounds__(256) void gemm32_mfma(const unsigned short* __restrict__ Xb,
                                                   const unsigned short* __restrict__ Wt2,
                                                   const float* __restrict__ asrc,
                                                   const float* __restrict__ adst,
                                                   unsigned short* __restrict__ H2b,
                                                   float* __restrict__ ALS,
                                                   float* __restrict__ ALD) {
    int wave = threadIdx.x >> 6;
    int lane = threadIdx.x & 63;
    int l15 = lane & 15;
    int q = lane >> 4;
    int r0 = (blockIdx.x * 4 + wave) * 16;   // 625*4*16 = 40000 exact

    f32x4 acc[2];
    acc[0] = (f32x4){0.f, 0.f, 0.f, 0.f};
    acc[1] = (f32x4){0.f, 0.f, 0.f, 0.f};

    const unsigned short* xrow = Xb + (long)(r0 + l15) * 128 + q * 8;
    const unsigned short* wrow = Wt2 + (long)l15 * 128 + q * 8;
#pragma unroll
    for (int kt = 0; kt < 4; ++kt) {
        bf16x8 a = *(const bf16x8*)(xrow + kt * 32);
#pragma unroll
        for (int t = 0; t < 2; ++t) {
            bf16x8 b = *(const bf16x8*)(wrow + (long)t * 16 * 128 + kt * 32);
            acc[t] = __builtin_amdgcn_mfma_f32_16x16x32_bf16(a, b, acc[t], 0, 0, 0);
        }
    }

    float as0 = asrc[l15], as1 = asrc[16 + l15];
    float ad0 = adst[l15], ad1 = adst[16 + l15];
#pragma unroll
    for (int t = 0; t < 2; ++t)
#pragma unroll
        for (int i = 0; i < 4; ++i)
            H2b[(long)(r0 + q * 4 + i) * 32 + t * 16 + l15] = f2bf(acc[t][i]);

#pragma unroll
    for (int i = 0; i < 4; ++i) {
        float ps = acc[0][i] * as0 + acc[1][i] * as1;
        float pd = acc[0][i] * ad0 + acc[1][i] * ad1;
#pragma unroll
        for (int m = 1; m < 16; m <<= 1) {
            ps += __shfl_xor(ps, m, 16);
            pd += __shfl_xor(pd, m, 16);
        }
        if (l15 == 0) {
            int r = r0 + q * 4 + i;
            ALS[r] = ps;
            ALD[r] = pd;
        }
    }
}

// ---------------- Edge aggregation, CSR by dst, batched-gather ----------------
__global__ __launch_bounds__(256) void agg128(const unsigned short* __restrict__ Hb,
                                              const float* __restrict__ ALS,
                                              const float* __restrict__ ALD,
                                              const int* __restrict__ offs,
                                              const int* __restrict__ ssrc,
                                              const float* __restrict__ bias,
                                              unsigned short* __restrict__ OUTb) {
    int n = blockIdx.x * 4 + (threadIdx.x >> 6);
    n = __builtin_amdgcn_readfirstlane(n);
    if (n >= N_NODES) return;
    int lane = threadIdx.x & 63;
    int c = lane * 2;
    int head = lane >> 4;
    int e16 = lane & 15;
    float aldh = ALD[n * 4 + head];
    int j0 = __builtin_amdgcn_readfirstlane(offs[n]);
    int j1 = __builtin_amdgcn_readfirstlane(offs[n + 1]);
    float a0 = 0.f, a1 = 0.f, dsum = 0.f;
    for (int jb = j0; jb < j1; jb += 16) {
        int j = jb + e16;
        int jc = (j < j1) ? j : (j1 - 1);
        int s = ssrc[jc];
        float4 als4 = *(const float4*)(ALS + (long)s * 4);
        float alsv = (head == 0) ? als4.x : (head == 1) ? als4.y
                   : (head == 2) ? als4.z : als4.w;
        float e = alsv + aldh;
        e = (e > 0.f) ? e : 0.2f * e;
        float w = (j < j1) ? __expf(e) : 0.f;
        int st[16]; float wt[16];
#pragma unroll
        for (int t = 0; t < 16; ++t) {
            st[t] = __shfl(s, t, 16);
            wt[t] = __shfl(w, t, 16);
        }
        unsigned int hv[16];
#pragma unroll
        for (int t = 0; t < 16; ++t)
            hv[t] = *(const unsigned int*)(Hb + (long)st[t] * 128 + c);
#pragma unroll
        for (int t = 0; t < 16; ++t) {
            float h0 = bf2f((unsigned short)(hv[t] & 0xFFFF));
            float h1 = bf2f((unsigned short)(hv[t] >> 16));
            dsum += wt[t];
            a0 += wt[t] * h0;
            a1 += wt[t] * h1;
        }
    }
    float inv = 1.0f / dsum;
    float o0 = a0 * inv + bias[c];
    float o1 = a1 * inv + bias[c + 1];
    o0 = (o0 > 0.f) ? o0 : (__expf(o0) - 1.f);
    o1 = (o1 > 0.f) ? o1 : (__expf(o1) - 1.f);
    ushort2 ob; ob.x = f2bf(o0); ob.y = f2bf(o1);
    *(ushort2*)(OUTb + (long)n * 128 + c) = ob;
}

__global__ __launch_bounds__(256) void agg32(const unsigned short* __restrict__ H2b,
                                             const float* __restrict__ ALS,
                                             const float* __restrict__ ALD,
                                             const int* __restrict__ offs,
                                             const int* __restrict__ ssrc,
                                             const float* __restrict__ bias,
                                             float* __restrict__ OUT) {
    int wv = blockIdx.x * 4 + (threadIdx.x >> 6);
    int lane = threadIdx.x & 63;
    int col = lane & 31;
    int half = lane >> 5;
    int e16 = lane & 15;
    int n = wv * 2 + half;
    if (n >= N_NODES) return;
    float aldn = ALD[n];
    int j0 = offs[n], j1 = offs[n + 1];
    float a = 0.f, dsum = 0.f;
    for (int jb = j0; jb < j1; jb += 16) {
        int j = jb + e16;
        int jc = (j < j1) ? j : (j1 - 1);
        int s = ssrc[jc];
        float e = ALS[s] + aldn;
        e = (e > 0.f) ? e : 0.2f * e;
        float w = (j < j1) ? __expf(e) : 0.f;
        int st[16]; float wt[16];
#pragma unroll
        for (int t = 0; t < 16; ++t) {
            st[t] = __shfl(s, t, 16);
            wt[t] = __shfl(w, t, 16);
        }
        unsigned short hv[16];
#pragma unroll
        for (int t = 0; t < 16; ++t)
            hv[t] = H2b[st[t] * 32 + col];
#pragma unroll
        for (int t = 0; t < 16; ++t) {
            dsum += wt[t];
            a += wt[t] * bf2f(hv[t]);
        }
    }
    float o = a / dsum + bias[col];
    o = (o > 0.f) ? o : (__expf(o) - 1.f);
    OUT[n * 32 + col] = o;
}

// ---------------- Pooling + MLP ----------------
__global__ __launch_bounds__(256) void pool_kernel(const float* __restrict__ H3,
                                                   const int* __restrict__ batch,
                                                   float* __restrict__ gsum,
                                                   float* __restrict__ gcnt) {
    const int CHUNK = 40;
    int gid = (blockIdx.x * 256 + threadIdx.x) >> 5;
    int c = threadIdx.x & 31;
    int n0 = gid * CHUNK;
    if (n0 >= N_NODES) return;
    int n1 = n0 + CHUNK;
    if (n1 > N_NODES) n1 = N_NODES;
    int cur = batch[n0];
    float acc = 0.f;
    int cnt = 0;
    for (int n = n0; n < n1; ++n) {
        int b = batch[n];
        if (b != cur) {
            atomicAdd(&gsum[cur * 32 + c], acc);
            if (c == 0) atomicAdd(&gcnt[cur], (float)cnt);
            cur = b; acc = 0.f; cnt = 0;
        }
        acc += H3[n * 32 + c];
        cnt++;
    }
    atomicAdd(&gsum[cur * 32 + c], acc);
    if (c == 0) atomicAdd(&gcnt[cur], (float)cnt);
}

__global__ __launch_bounds__(256) void mlp_kernel(const float* __restrict__ gsum,
                                                  const float* __restrict__ gcnt,
                                                  const float* __restrict__ l1w,
                                                  const float* __restrict__ l1b,
                                                  const float* __restrict__ l2w,
                                                  const float* __restrict__ l2b,
                                                  float* __restrict__ out) {
    __shared__ float g[NUM_GRAPHS * 32];
    __shared__ float t1[NUM_GRAPHS * 128];
    int tid = threadIdx.x;
    for (int i = tid; i < NUM_GRAPHS * 32; i += 256) {
        float c = gcnt[i >> 5];
        g[i] = gsum[i] / fmaxf(c, 1.0f);
    }
    __syncthreads();
    for (int i = tid; i < NUM_GRAPHS * 128; i += 256) {
        int r = i >> 7, j = i & 127;
        float a = l1b[j];
        for (int k = 0; k < 32; ++k) a += g[r * 32 + k] * l1w[k * 128 + j];
        t1[i] = fmaxf(a, 0.f);
    }
    __syncthreads();
    for (int i = tid; i < NUM_GRAPHS * 8; i += 256) {
        int r = i >> 3, j = i & 7;
        float a = l2b[j];
        for (int k = 0; k < 128; ++k) a += t1[r * 128 + k] * l2w[k * 8 + j];
        out[i] = a;
    }
}

// ---------------- host ----------------

extern "C" void kernel_launch(void* const* d_in, const int* in_sizes, int n_in,
                              void* d_out, int out_size, void* d_ws, size_t ws_size,
                              hipStream_t stream) {
    const float* x      = (const float*)d_in[0];
    const int*   eidx   = (const int*)d_in[1];
    const int*   batch  = (const int*)d_in[2];
    const float* W0     = (const float*)d_in[3];
    const float* asrc0  = (const float*)d_in[4];
    const float* adst0  = (const float*)d_in[5];
    const float* b0     = (const float*)d_in[6];
    const float* W1     = (const float*)d_in[7];
    const float* asrc1  = (const float*)d_in[8];
    const float* adst1  = (const float*)d_in[9];
    const float* b1     = (const float*)d_in[10];
    const float* W2     = (const float*)d_in[11];
    const float* asrc2  = (const float*)d_in[12];
    const float* adst2  = (const float*)d_in[13];
    const float* b2     = (const float*)d_in[14];
    const float* l1w    = (const float*)d_in[15];
    const float* l1b    = (const float*)d_in[16];
    const float* l2w    = (const float*)d_in[17];
    const float* l2b    = (const float*)d_in[18];
    float* out = (float*)d_out;

    const int* esrc = eidx;
    const int* edst = eidx + N_EDGES;

    // workspace layout: fp32, then one contiguous zeroed int/f32 region, then rest
    float* ALS  = (float*)d_ws;                       // N*4
    float* ALD  = ALS + N_NODES * 4;                  // N*4
    float* h3   = ALD + N_NODES * 4;                  // N*32
    int* counts = (int*)(h3 + (long)N_NODES * 32);    // N      <- zero from here
    int* pos    = counts + N_NODES;                   // N
    float* gsum = (float*)(pos + N_NODES);            // 64*32
    float* gcnt = gsum + NUM_GRAPHS * 32;             // 64     <- zero to here
    int* offs   = (int*)(gcnt + NUM_GRAPHS);          // N+1
    int* bsum   = offs + (N_NODES + 1);               // SCAN_BLOCKS
    int* bofs   = bsum + SCAN_BLOCKS;                 // SCAN_BLOCKS
    int* ssrc   = bofs + SCAN_BLOCKS;                 // E_TOT
    // align bf16 region to 16B
    uintptr_t p = (uintptr_t)(ssrc + E_TOT);
    p = (p + 15) & ~(uintptr_t)15;
    unsigned short* Xb   = (unsigned short*)p;              // N*128 bf16
    unsigned short* Hb   = Xb + (long)N_NODES * 128;        // N*128 bf16
    unsigned short* OUTb = Hb + (long)N_NODES * 128;        // N*128 bf16
    unsigned short* H2b  = OUTb + (long)N_NODES * 128;      // N*32 bf16
    unsigned short* Wt0  = H2b + (long)N_NODES * 32;        // 128*128 bf16
    unsigned short* Wt1  = Wt0 + 128 * 128;                 // 128*128 bf16
    unsigned short* Wt2  = Wt1 + 128 * 128;                 // 32*128 bf16

    // single zeroing pass: counts, pos, gsum, gcnt (contiguous)
    size_t zbytes = (size_t)(2 * N_NODES + NUM_GRAPHS * 32 + NUM_GRAPHS) * 4;
    hipMemsetAsync(counts, 0, zbytes, stream);

    // conversions
    cvt_x<<<5000, 256, 0, stream>>>(x, Xb);
    cvt_w<<<144, 256, 0, stream>>>(W0, W1, W2, Wt0, Wt1, Wt2);

    // CSR build
    int qblocks = (EQ4 + 255) / 256;
    hist_kernel<<<qblocks, 256, 0, stream>>>(edst, counts);
    bsum_kernel<<<SCAN_BLOCKS, 256, 0, stream>>>(counts, bsum);
    bscan_kernel<<<1, 256, 0, stream>>>(bsum, bofs);
    boffs_kernel<<<SCAN_BLOCKS, 256, 0, stream>>>(counts, bofs, offs);
    scatter_kernel<<<qblocks, 256, 0, stream>>>(esrc, edst, offs, pos, ssrc);

    // layer 0
    gemm128_mfma<<<625, 256, 0, stream>>>(Xb, Wt0, asrc0, adst0, Hb, ALS, ALD);
    agg128<<<10000, 256, 0, stream>>>(Hb, ALS, ALD, offs, ssrc, b0, OUTb);

    // layer 1
    gemm128_mfma<<<625, 256, 0, stream>>>(OUTb, Wt1, asrc1, adst1, Hb, ALS, ALD);
    agg128<<<10000, 256, 0, stream>>>(Hb, ALS, ALD, offs, ssrc, b1, OUTb);

    // layer 2
    gemm32_mfma<<<625, 256, 0, stream>>>(OUTb, Wt2, asrc2, adst2, H2b, ALS, ALD);
    agg32<<<5000, 256, 0, stream>>>(H2b, ALS, ALD, offs, ssrc, b2, h3);

    // pool + MLP
    pool_kernel<<<125, 256, 0, stream>>>(h3, batch, gsum, gcnt);
    mlp_kernel<<<1, 256, 0, stream>>>(gsum, gcnt, l1w, l1b, l2w, l2b, out);
}

// Round 8
// 314.106 us; speedup vs baseline: 2.4712x; 1.0902x over previous
//
#include <hip/hip_runtime.h>
#include <hip/hip_bf16.h>

#define N_NODES 40000
#define N_EDGES 640000
#define E_TOT   (N_EDGES + N_NODES)
#define NUM_GRAPHS 64
#define SCAN_BLOCKS 160
#define SCAN_CHUNK  250   // 160*250 = 40000

typedef __attribute__((ext_vector_type(8))) short bf16x8;
typedef __attribute__((ext_vector_type(4))) float f32x4;

__device__ inline float bf2f(unsigned short u) {
    union { unsigned int i; float f; } v; v.i = ((unsigned int)u) << 16; return v.f;
}
__device__ inline unsigned short f2bf(float f) {
    union { float f; unsigned int i; } v; v.f = f;
    unsigned int r = v.i + 0x7FFF + ((v.i >> 16) & 1);
    return (unsigned short)(r >> 16);
}

// ---------------- conversions ----------------

__global__ __launch_bounds__(256) void cvt_x(const float* __restrict__ x,
                                             unsigned short* __restrict__ xb) {
    int i = blockIdx.x * 256 + threadIdx.x;   // over float4s: N*128/4 = 1.28M
    float4 v = ((const float4*)x)[i];
    ushort4 o;
    o.x = f2bf(v.x); o.y = f2bf(v.y); o.z = f2bf(v.z); o.w = f2bf(v.w);
    ((ushort4*)xb)[i] = o;
}

// Wt[n*K+k] = bf16(W[k*N+n]) for W0 (128x128), W1 (128x128), W2 (128x32)
__global__ __launch_bounds__(256) void cvt_w(const float* __restrict__ W0,
                                             const float* __restrict__ W1,
                                             const float* __restrict__ W2,
                                             unsigned short* __restrict__ Wt0,
                                             unsigned short* __restrict__ Wt1,
                                             unsigned short* __restrict__ Wt2) {
    int idx = blockIdx.x * 256 + threadIdx.x;   // 36864 total, grid 144
    if (idx < 16384) {
        int n = idx >> 7, k = idx & 127;
        Wt0[idx] = f2bf(W0[k * 128 + n]);
    } else if (idx < 32768) {
        int i = idx - 16384;
        int n = i >> 7, k = i & 127;
        Wt1[i] = f2bf(W1[k * 128 + n]);
    } else if (idx < 36864) {
        int i = idx - 32768;
        int n = i >> 7, k = i & 127;   // n in [0,32)
        Wt2[i] = f2bf(W2[k * 32 + n]);
    }
}

// ---------------- CSR build ----------------

// hist + rank fusion: the atomic's return value is this edge's slot within
// its dst segment. rank written coalesced; counts ends as the histogram.
__global__ __launch_bounds__(256) void hist_rank_kernel(const int* __restrict__ edst,
                                                        int* __restrict__ counts,
                                                        int* __restrict__ rank) {
    int e = blockIdx.x * 256 + threadIdx.x;
    if (e >= E_TOT) return;
    int d = (e < N_EDGES) ? edst[e] : (e - N_EDGES);
    rank[e] = atomicAdd(&counts[d], 1);
}

__global__ __launch_bounds__(256) void bsum_kernel(const int* __restrict__ counts,
                                                   int* __restrict__ bsum) {
    __shared__ int ws[4];
    int b = blockIdx.x, tid = threadIdx.x;
    int idx = b * SCAN_CHUNK + tid;
    int v = (tid < SCAN_CHUNK) ? counts[idx] : 0;
#pragma unroll
    for (int off = 32; off >= 1; off >>= 1) v += __shfl_down(v, off, 64);
    if ((tid & 63) == 0) ws[tid >> 6] = v;
    __syncthreads();
    if (tid == 0) bsum[b] = ws[0] + ws[1] + ws[2] + ws[3];
}

__global__ __launch_bounds__(256) void bscan_kernel(const int* __restrict__ bsum,
                                                    int* __restrict__ bofs) {
    __shared__ int s[256];
    int tid = threadIdx.x;
    int v = (tid < SCAN_BLOCKS) ? bsum[tid] : 0;
    s[tid] = v;
    __syncthreads();
    for (int off = 1; off < 256; off <<= 1) {
        int t = (tid >= off) ? s[tid - off] : 0;
        __syncthreads();
        s[tid] += t;
        __syncthreads();
    }
    if (tid < SCAN_BLOCKS) bofs[tid] = s[tid] - v;  // exclusive
}

__global__ __launch_bounds__(256) void boffs_kernel(const int* __restrict__ counts,
                                                    const int* __restrict__ bofs,
                                                    int* __restrict__ offs) {
    __shared__ int s[256];
    int b = blockIdx.x, tid = threadIdx.x;
    int idx = b * SCAN_CHUNK + tid;
    int v = (tid < SCAN_CHUNK) ? counts[idx] : 0;
    s[tid] = v;
    __syncthreads();
    for (int off = 1; off < 256; off <<= 1) {
        int t = (tid >= off) ? s[tid - off] : 0;
        __syncthreads();
        s[tid] += t;
        __syncthreads();
    }
    int incl = s[tid];
    int base = bofs[b];
    if (tid < SCAN_CHUNK) {
        offs[idx] = base + incl - v;
        if (idx == N_NODES - 1) offs[N_NODES] = base + incl;
    }
}

// atomic-free scatter: slot = offs[d] + rank[e]
__global__ __launch_bounds__(256) void scatter_kernel(const int* __restrict__ esrc,
                                                      const int* __restrict__ edst,
                                                      const int* __restrict__ offs,
                                                      const int* __restrict__ rank,
                                                      int* __restrict__ ssrc) {
    int e = blockIdx.x * 256 + threadIdx.x;
    if (e >= E_TOT) return;
    int d, s;
    if (e < N_EDGES) { d = edst[e]; s = esrc[e]; }
    else             { d = e - N_EDGES; s = d; }
    ssrc[offs[d] + rank[e]] = s;
}

// ---------------- MFMA GEMM + attention scores (128 -> 128) ----------------
// One wave -> 16 rows x 128 cols. C/D layout: col = lane&15, row = quad*4+reg.
__global__ __launch_bounds__(256) void gemm128_mfma(const unsigned short* __restrict__ Xb,
                                                    const unsigned short* __restrict__ Wt,
                                                    const float* __restrict__ asrc,
                                                    const float* __restrict__ adst,
                                                    unsigned short* __restrict__ Hb,
                                                    float* __restrict__ ALS,
                                                    float* __restrict__ ALD) {
    int wave = threadIdx.x >> 6;
    int lane = threadIdx.x & 63;
    int l15 = lane & 15;
    int q = lane >> 4;
    int r0 = (blockIdx.x * 4 + wave) * 16;   // 625*4*16 = 40000 exact

    f32x4 acc[8];
#pragma unroll
    for (int t = 0; t < 8; ++t) acc[t] = (f32x4){0.f, 0.f, 0.f, 0.f};

    float asv[8], adv[8];
#pragma unroll
    for (int t = 0; t < 8; ++t) {
        int c = t * 16 + l15;
        asv[t] = asrc[c];
        adv[t] = adst[c];
    }

    const unsigned short* xrow = Xb + (long)(r0 + l15) * 128 + q * 8;
    const unsigned short* wrow = Wt + (long)l15 * 128 + q * 8;
#pragma unroll
    for (int kt = 0; kt < 4; ++kt) {
        bf16x8 a = *(const bf16x8*)(xrow + kt * 32);
#pragma unroll
        for (int t = 0; t < 8; ++t) {
            bf16x8 b = *(const bf16x8*)(wrow + (long)t * 16 * 128 + kt * 32);
            acc[t] = __builtin_amdgcn_mfma_f32_16x16x32_bf16(a, b, acc[t], 0, 0, 0);
        }
    }

#pragma unroll
    for (int t = 0; t < 8; ++t)
#pragma unroll
        for (int i = 0; i < 4; ++i)
            Hb[(long)(r0 + q * 4 + i) * 128 + t * 16 + l15] = f2bf(acc[t][i]);

#pragma unroll
    for (int i = 0; i < 4; ++i) {
        float ps0 = acc[0][i] * asv[0] + acc[1][i] * asv[1];
        float ps1 = acc[2][i] * asv[2] + acc[3][i] * asv[3];
        float ps2 = acc[4][i] * asv[4] + acc[5][i] * asv[5];
        float ps3 = acc[6][i] * asv[6] + acc[7][i] * asv[7];
        float pd0 = acc[0][i] * adv[0] + acc[1][i] * adv[1];
        float pd1 = acc[2][i] * adv[2] + acc[3][i] * adv[3];
        float pd2 = acc[4][i] * adv[4] + acc[5][i] * adv[5];
        float pd3 = acc[6][i] * adv[6] + acc[7][i] * adv[7];
#pragma unroll
        for (int m = 1; m < 16; m <<= 1) {
            ps0 += __shfl_xor(ps0, m, 16); ps1 += __shfl_xor(ps1, m, 16);
            ps2 += __shfl_xor(ps2, m, 16); ps3 += __shfl_xor(ps3, m, 16);
            pd0 += __shfl_xor(pd0, m, 16); pd1 += __shfl_xor(pd1, m, 16);
            pd2 += __shfl_xor(pd2, m, 16); pd3 += __shfl_xor(pd3, m, 16);
        }
        if (l15 == 0) {
            int r = r0 + q * 4 + i;
            *(float4*)(ALS + (long)r * 4) = make_float4(ps0, ps1, ps2, ps3);
            *(float4*)(ALD + (long)r * 4) = make_float4(pd0, pd1, pd2, pd3);
        }
    }
}

// ---------------- MFMA GEMM (128 -> 32, 1 head) ----------------
__global__ __launch_bounds__(256) void gemm32_mfma(const unsigned short* __restrict__ Xb,
                                                   const unsigned short* __restrict__ Wt2,
                                                   const float* __restrict__ asrc,
                                                   const float* __restrict__ adst,
                                                   unsigned short* __restrict__ H2b,
                                                   float* __restrict__ ALS,
                                                   float* __restrict__ ALD) {
    int wave = threadIdx.x >> 6;
    int lane = threadIdx.x & 63;
    int l15 = lane & 15;
    int q = lane >> 4;
    int r0 = (blockIdx.x * 4 + wave) * 16;   // 625*4*16 = 40000 exact

    f32x4 acc[2];
    acc[0] = (f32x4){0.f, 0.f, 0.f, 0.f};
    acc[1] = (f32x4){0.f, 0.f, 0.f, 0.f};

    const unsigned short* xrow = Xb + (long)(r0 + l15) * 128 + q * 8;
    const unsigned short* wrow = Wt2 + (long)l15 * 128 + q * 8;
#pragma unroll
    for (int kt = 0; kt < 4; ++kt) {
        bf16x8 a = *(const bf16x8*)(xrow + kt * 32);
#pragma unroll
        for (int t = 0; t < 2; ++t) {
            bf16x8 b = *(const bf16x8*)(wrow + (long)t * 16 * 128 + kt * 32);
            acc[t] = __builtin_amdgcn_mfma_f32_16x16x32_bf16(a, b, acc[t], 0, 0, 0);
        }
    }

    float as0 = asrc[l15], as1 = asrc[16 + l15];
    float ad0 = adst[l15], ad1 = adst[16 + l15];
#pragma unroll
    for (int t = 0; t < 2; ++t)
#pragma unroll
        for (int i = 0; i < 4; ++i)
            H2b[(long)(r0 + q * 4 + i) * 32 + t * 16 + l15] = f2bf(acc[t][i]);

#pragma unroll
    for (int i = 0; i < 4; ++i) {
        float ps = acc[0][i] * as0 + acc[1][i] * as1;
        float pd = acc[0][i] * ad0 + acc[1][i] * ad1;
#pragma unroll
        for (int m = 1; m < 16; m <<= 1) {
            ps += __shfl_xor(ps, m, 16);
            pd += __shfl_xor(pd, m, 16);
        }
        if (l15 == 0) {
            int r = r0 + q * 4 + i;
            ALS[r] = ps;
            ALD[r] = pd;
        }
    }
}

// ---------------- Edge aggregation, CSR by dst, batched-gather ----------------
__global__ __launch_bounds__(256) void agg128(const unsigned short* __restrict__ Hb,
                                              const float* __restrict__ ALS,
                                              const float* __restrict__ ALD,
                                              const int* __restrict__ offs,
                                              const int* __restrict__ ssrc,
                                              const float* __restrict__ bias,
                                              unsigned short* __restrict__ OUTb) {
    int n = blockIdx.x * 4 + (threadIdx.x >> 6);
    n = __builtin_amdgcn_readfirstlane(n);
    if (n >= N_NODES) return;
    int lane = threadIdx.x & 63;
    int c = lane * 2;
    int head = lane >> 4;
    int e16 = lane & 15;
    float aldh = ALD[n * 4 + head];
    int j0 = __builtin_amdgcn_readfirstlane(offs[n]);
    int j1 = __builtin_amdgcn_readfirstlane(offs[n + 1]);
    float a0 = 0.f, a1 = 0.f, dsum = 0.f;
    for (int jb = j0; jb < j1; jb += 16) {
        int j = jb + e16;
        int jc = (j < j1) ? j : (j1 - 1);
        int s = ssrc[jc];
        float4 als4 = *(const float4*)(ALS + (long)s * 4);
        float alsv = (head == 0) ? als4.x : (head == 1) ? als4.y
                   : (head == 2) ? als4.z : als4.w;
        float e = alsv + aldh;
        e = (e > 0.f) ? e : 0.2f * e;
        float w = (j < j1) ? __expf(e) : 0.f;
        int st[16]; float wt[16];
#pragma unroll
        for (int t = 0; t < 16; ++t) {
            st[t] = __shfl(s, t, 16);
            wt[t] = __shfl(w, t, 16);
        }
        unsigned int hv[16];
#pragma unroll
        for (int t = 0; t < 16; ++t)
            hv[t] = *(const unsigned int*)(Hb + (long)st[t] * 128 + c);
#pragma unroll
        for (int t = 0; t < 16; ++t) {
            float h0 = bf2f((unsigned short)(hv[t] & 0xFFFF));
            float h1 = bf2f((unsigned short)(hv[t] >> 16));
            dsum += wt[t];
            a0 += wt[t] * h0;
            a1 += wt[t] * h1;
        }
    }
    float inv = 1.0f / dsum;
    float o0 = a0 * inv + bias[c];
    float o1 = a1 * inv + bias[c + 1];
    o0 = (o0 > 0.f) ? o0 : (__expf(o0) - 1.f);
    o1 = (o1 > 0.f) ? o1 : (__expf(o1) - 1.f);
    ushort2 ob; ob.x = f2bf(o0); ob.y = f2bf(o1);
    *(ushort2*)(OUTb + (long)n * 128 + c) = ob;
}

__global__ __launch_bounds__(256) void agg32(const unsigned short* __restrict__ H2b,
                                             const float* __restrict__ ALS,
                                             const float* __restrict__ ALD,
                                             const int* __restrict__ offs,
                                             const int* __restrict__ ssrc,
                                             const float* __restrict__ bias,
                                             float* __restrict__ OUT) {
    int wv = blockIdx.x * 4 + (threadIdx.x >> 6);
    int lane = threadIdx.x & 63;
    int col = lane & 31;
    int half = lane >> 5;
    int e16 = lane & 15;
    int n = wv * 2 + half;
    if (n >= N_NODES) return;
    float aldn = ALD[n];
    int j0 = offs[n], j1 = offs[n + 1];
    float a = 0.f, dsum = 0.f;
    for (int jb = j0; jb < j1; jb += 16) {
        int j = jb + e16;
        int jc = (j < j1) ? j : (j1 - 1);
        int s = ssrc[jc];
        float e = ALS[s] + aldn;
        e = (e > 0.f) ? e : 0.2f * e;
        float w = (j < j1) ? __expf(e) : 0.f;
        int st[16]; float wt[16];
#pragma unroll
        for (int t = 0; t < 16; ++t) {
            st[t] = __shfl(s, t, 16);
            wt[t] = __shfl(w, t, 16);
        }
        unsigned short hv[16];
#pragma unroll
        for (int t = 0; t < 16; ++t)
            hv[t] = H2b[st[t] * 32 + col];
#pragma unroll
        for (int t = 0; t < 16; ++t) {
            dsum += wt[t];
            a += wt[t] * bf2f(hv[t]);
        }
    }
    float o = a / dsum + bias[col];
    o = (o > 0.f) ? o : (__expf(o) - 1.f);
    OUT[n * 32 + col] = o;
}

// ---------------- Pooling + MLP ----------------
__global__ __launch_bounds__(256) void pool_kernel(const float* __restrict__ H3,
                                                   const int* __restrict__ batch,
                                                   float* __restrict__ gsum,
                                                   float* __restrict__ gcnt) {
    const int CHUNK = 40;
    int gid = (blockIdx.x * 256 + threadIdx.x) >> 5;
    int c = threadIdx.x & 31;
    int n0 = gid * CHUNK;
    if (n0 >= N_NODES) return;
    int n1 = n0 + CHUNK;
    if (n1 > N_NODES) n1 = N_NODES;
    int cur = batch[n0];
    float acc = 0.f;
    int cnt = 0;
    for (int n = n0; n < n1; ++n) {
        int b = batch[n];
        if (b != cur) {
            atomicAdd(&gsum[cur * 32 + c], acc);
            if (c == 0) atomicAdd(&gcnt[cur], (float)cnt);
            cur = b; acc = 0.f; cnt = 0;
        }
        acc += H3[n * 32 + c];
        cnt++;
    }
    atomicAdd(&gsum[cur * 32 + c], acc);
    if (c == 0) atomicAdd(&gcnt[cur], (float)cnt);
}

__global__ __launch_bounds__(256) void mlp_kernel(const float* __restrict__ gsum,
                                                  const float* __restrict__ gcnt,
                                                  const float* __restrict__ l1w,
                                                  const float* __restrict__ l1b,
                                                  const float* __restrict__ l2w,
                                                  const float* __restrict__ l2b,
                                                  float* __restrict__ out) {
    __shared__ float g[NUM_GRAPHS * 32];
    __shared__ float t1[NUM_GRAPHS * 128];
    int tid = threadIdx.x;
    for (int i = tid; i < NUM_GRAPHS * 32; i += 256) {
        float c = gcnt[i >> 5];
        g[i] = gsum[i] / fmaxf(c, 1.0f);
    }
    __syncthreads();
    for (int i = tid; i < NUM_GRAPHS * 128; i += 256) {
        int r = i >> 7, j = i & 127;
        float a = l1b[j];
        for (int k = 0; k < 32; ++k) a += g[r * 32 + k] * l1w[k * 128 + j];
        t1[i] = fmaxf(a, 0.f);
    }
    __syncthreads();
    for (int i = tid; i < NUM_GRAPHS * 8; i += 256) {
        int r = i >> 3, j = i & 7;
        float a = l2b[j];
        for (int k = 0; k < 128; ++k) a += t1[r * 128 + k] * l2w[k * 8 + j];
        out[i] = a;
    }
}

// ---------------- host ----------------

extern "C" void kernel_launch(void* const* d_in, const int* in_sizes, int n_in,
                              void* d_out, int out_size, void* d_ws, size_t ws_size,
                              hipStream_t stream) {
    const float* x      = (const float*)d_in[0];
    const int*   eidx   = (const int*)d_in[1];
    const int*   batch  = (const int*)d_in[2];
    const float* W0     = (const float*)d_in[3];
    const float* asrc0  = (const float*)d_in[4];
    const float* adst0  = (const float*)d_in[5];
    const float* b0     = (const float*)d_in[6];
    const float* W1     = (const float*)d_in[7];
    const float* asrc1  = (const float*)d_in[8];
    const float* adst1  = (const float*)d_in[9];
    const float* b1     = (const float*)d_in[10];
    const float* W2     = (const float*)d_in[11];
    const float* asrc2  = (const float*)d_in[12];
    const float* adst2  = (const float*)d_in[13];
    const float* b2     = (const float*)d_in[14];
    const float* l1w    = (const float*)d_in[15];
    const float* l1b    = (const float*)d_in[16];
    const float* l2w    = (const float*)d_in[17];
    const float* l2b    = (const float*)d_in[18];
    float* out = (float*)d_out;

    const int* esrc = eidx;
    const int* edst = eidx + N_EDGES;

    // workspace layout
    float* ALS  = (float*)d_ws;                       // N*4
    float* ALD  = ALS + N_NODES * 4;                  // N*4
    float* h3   = ALD + N_NODES * 4;                  // N*32
    int* counts = (int*)(h3 + (long)N_NODES * 32);    // N      <- zero from here
    float* gsum = (float*)(counts + N_NODES);         // 64*32
    float* gcnt = gsum + NUM_GRAPHS * 32;             // 64     <- zero to here
    int* offs   = (int*)(gcnt + NUM_GRAPHS);          // N+1
    int* bsum   = offs + (N_NODES + 1);               // SCAN_BLOCKS
    int* bofs   = bsum + SCAN_BLOCKS;                 // SCAN_BLOCKS
    int* rank   = bofs + SCAN_BLOCKS;                 // E_TOT
    int* ssrc   = rank + E_TOT;                       // E_TOT
    // align bf16 region to 16B
    uintptr_t p = (uintptr_t)(ssrc + E_TOT);
    p = (p + 15) & ~(uintptr_t)15;
    unsigned short* Xb   = (unsigned short*)p;              // N*128 bf16
    unsigned short* Hb   = Xb + (long)N_NODES * 128;        // N*128 bf16
    unsigned short* OUTb = Hb + (long)N_NODES * 128;        // N*128 bf16
    unsigned short* H2b  = OUTb + (long)N_NODES * 128;      // N*32 bf16
    unsigned short* Wt0  = H2b + (long)N_NODES * 32;        // 128*128 bf16
    unsigned short* Wt1  = Wt0 + 128 * 128;                 // 128*128 bf16
    unsigned short* Wt2  = Wt1 + 128 * 128;                 // 32*128 bf16

    // single zeroing pass: counts, gsum, gcnt (contiguous)
    size_t zbytes = (size_t)(N_NODES + NUM_GRAPHS * 32 + NUM_GRAPHS) * 4;
    hipMemsetAsync(counts, 0, zbytes, stream);

    // conversions
    cvt_x<<<5000, 256, 0, stream>>>(x, Xb);
    cvt_w<<<144, 256, 0, stream>>>(W0, W1, W2, Wt0, Wt1, Wt2);

    // CSR build
    int eblocks = (E_TOT + 255) / 256;
    hist_rank_kernel<<<eblocks, 256, 0, stream>>>(edst, counts, rank);
    bsum_kernel<<<SCAN_BLOCKS, 256, 0, stream>>>(counts, bsum);
    bscan_kernel<<<1, 256, 0, stream>>>(bsum, bofs);
    boffs_kernel<<<SCAN_BLOCKS, 256, 0, stream>>>(counts, bofs, offs);
    scatter_kernel<<<eblocks, 256, 0, stream>>>(esrc, edst, offs, rank, ssrc);

    // layer 0
    gemm128_mfma<<<625, 256, 0, stream>>>(Xb, Wt0, asrc0, adst0, Hb, ALS, ALD);
    agg128<<<10000, 256, 0, stream>>>(Hb, ALS, ALD, offs, ssrc, b0, OUTb);

    // layer 1
    gemm128_mfma<<<625, 256, 0, stream>>>(OUTb, Wt1, asrc1, adst1, Hb, ALS, ALD);
    agg128<<<10000, 256, 0, stream>>>(Hb, ALS, ALD, offs, ssrc, b1, OUTb);

    // layer 2
    gemm32_mfma<<<625, 256, 0, stream>>>(OUTb, Wt2, asrc2, adst2, H2b, ALS, ALD);
    agg32<<<5000, 256, 0, stream>>>(H2b, ALS, ALD, offs, ssrc, b2, h3);

    // pool + MLP
    pool_kernel<<<125, 256, 0, stream>>>(h3, batch, gsum, gcnt);
    mlp_kernel<<<1, 256, 0, stream>>>(gsum, gcnt, l1w, l1b, l2w, l2b, out);
}

// Round 9
// 313.516 us; speedup vs baseline: 2.4759x; 1.0019x over previous
//
#include <hip/hip_runtime.h>
#include <hip/hip_bf16.h>

#define N_NODES 40000
#define N_EDGES 640000
#define E_TOT   (N_EDGES + N_NODES)
#define NUM_GRAPHS 64
#define SCAN_BLOCKS 160
#define SCAN_CHUNK  250   // 160*250 = 40000

// setup kernel partition
#define CVTX_BLOCKS 5000              // N*128/4 float4s / 256
#define CVTW_BLOCKS 144               // 36864 / 256
#define ZERO_INTS   (N_NODES + NUM_GRAPHS * 32 + NUM_GRAPHS)   // 42112
#define ZERO_BLOCKS ((ZERO_INTS + 255) / 256)                  // 165

typedef __attribute__((ext_vector_type(8))) short bf16x8;
typedef __attribute__((ext_vector_type(4))) float f32x4;

__device__ inline float bf2f(unsigned short u) {
    union { unsigned int i; float f; } v; v.i = ((unsigned int)u) << 16; return v.f;
}
__device__ inline unsigned short f2bf(float f) {
    union { float f; unsigned int i; } v; v.f = f;
    unsigned int r = v.i + 0x7FFF + ((v.i >> 16) & 1);
    return (unsigned short)(r >> 16);
}

// ---------------- fused setup: x->bf16, W transposes, zero counts/gsum/gcnt ----------------

__global__ __launch_bounds__(256) void setup_kernel(const float* __restrict__ x,
                                                    const float* __restrict__ W0,
                                                    const float* __restrict__ W1,
                                                    const float* __restrict__ W2,
                                                    unsigned short* __restrict__ Xb,
                                                    unsigned short* __restrict__ Wt0,
                                                    unsigned short* __restrict__ Wt1,
                                                    unsigned short* __restrict__ Wt2,
                                                    int* __restrict__ zbase) {
    int b = blockIdx.x;
    int tid = threadIdx.x;
    if (b < CVTX_BLOCKS) {
        int i = b * 256 + tid;
        float4 v = ((const float4*)x)[i];
        ushort4 o;
        o.x = f2bf(v.x); o.y = f2bf(v.y); o.z = f2bf(v.z); o.w = f2bf(v.w);
        ((ushort4*)Xb)[i] = o;
    } else if (b < CVTX_BLOCKS + CVTW_BLOCKS) {
        int idx = (b - CVTX_BLOCKS) * 256 + tid;
        if (idx < 16384) {
            int n = idx >> 7, k = idx & 127;
            Wt0[idx] = f2bf(W0[k * 128 + n]);
        } else if (idx < 32768) {
            int i = idx - 16384;
            int n = i >> 7, k = i & 127;
            Wt1[i] = f2bf(W1[k * 128 + n]);
        } else {
            int i = idx - 32768;
            int n = i >> 7, k = i & 127;   // n in [0,32)
            Wt2[i] = f2bf(W2[k * 32 + n]);
        }
    } else {
        int i = (b - CVTX_BLOCKS - CVTW_BLOCKS) * 256 + tid;
        if (i < ZERO_INTS) zbase[i] = 0;
    }
}

// ---------------- CSR build ----------------

// hist + rank fusion: atomic's return value = slot within dst segment.
__global__ __launch_bounds__(256) void hist_rank_kernel(const int* __restrict__ edst,
                                                        int* __restrict__ counts,
                                                        int* __restrict__ rank) {
    int e = blockIdx.x * 256 + threadIdx.x;
    if (e >= E_TOT) return;
    int d = (e < N_EDGES) ? edst[e] : (e - N_EDGES);
    rank[e] = atomicAdd(&counts[d], 1);
}

__global__ __launch_bounds__(256) void bsum_kernel(const int* __restrict__ counts,
                                                   int* __restrict__ bsum) {
    __shared__ int ws[4];
    int b = blockIdx.x, tid = threadIdx.x;
    int idx = b * SCAN_CHUNK + tid;
    int v = (tid < SCAN_CHUNK) ? counts[idx] : 0;
#pragma unroll
    for (int off = 32; off >= 1; off >>= 1) v += __shfl_down(v, off, 64);
    if ((tid & 63) == 0) ws[tid >> 6] = v;
    __syncthreads();
    if (tid == 0) bsum[b] = ws[0] + ws[1] + ws[2] + ws[3];
}

__global__ __launch_bounds__(256) void bscan_kernel(const int* __restrict__ bsum,
                                                    int* __restrict__ bofs) {
    __shared__ int s[256];
    int tid = threadIdx.x;
    int v = (tid < SCAN_BLOCKS) ? bsum[tid] : 0;
    s[tid] = v;
    __syncthreads();
    for (int off = 1; off < 256; off <<= 1) {
        int t = (tid >= off) ? s[tid - off] : 0;
        __syncthreads();
        s[tid] += t;
        __syncthreads();
    }
    if (tid < SCAN_BLOCKS) bofs[tid] = s[tid] - v;  // exclusive
}

__global__ __launch_bounds__(256) void boffs_kernel(const int* __restrict__ counts,
                                                    const int* __restrict__ bofs,
                                                    int* __restrict__ offs) {
    __shared__ int s[256];
    int b = blockIdx.x, tid = threadIdx.x;
    int idx = b * SCAN_CHUNK + tid;
    int v = (tid < SCAN_CHUNK) ? counts[idx] : 0;
    s[tid] = v;
    __syncthreads();
    for (int off = 1; off < 256; off <<= 1) {
        int t = (tid >= off) ? s[tid - off] : 0;
        __syncthreads();
        s[tid] += t;
        __syncthreads();
    }
    int incl = s[tid];
    int base = bofs[b];
    if (tid < SCAN_CHUNK) {
        offs[idx] = base + incl - v;
        if (idx == N_NODES - 1) offs[N_NODES] = base + incl;
    }
}

// atomic-free scatter: slot = offs[d] + rank[e]
__global__ __launch_bounds__(256) void scatter_kernel(const int* __restrict__ esrc,
                                                      const int* __restrict__ edst,
                                                      const int* __restrict__ offs,
                                                      const int* __restrict__ rank,
                                                      int* __restrict__ ssrc) {
    int e = blockIdx.x * 256 + threadIdx.x;
    if (e >= E_TOT) return;
    int d, s;
    if (e < N_EDGES) { d = edst[e]; s = esrc[e]; }
    else             { d = e - N_EDGES; s = d; }
    ssrc[offs[d] + rank[e]] = s;
}

// ---------------- MFMA GEMM + attention scores (128 -> 128) ----------------
// One wave -> 16 rows x 128 cols. C/D layout: col = lane&15, row = quad*4+reg.
// ALS/ALD written TRANSPOSED: ALS_t[head*N + r] (4B gathers in agg128).
__global__ __launch_bounds__(256) void gemm128_mfma(const unsigned short* __restrict__ Xb,
                                                    const unsigned short* __restrict__ Wt,
                                                    const float* __restrict__ asrc,
                                                    const float* __restrict__ adst,
                                                    unsigned short* __restrict__ Hb,
                                                    float* __restrict__ ALS_t,
                                                    float* __restrict__ ALD_t) {
    int wave = threadIdx.x >> 6;
    int lane = threadIdx.x & 63;
    int l15 = lane & 15;
    int q = lane >> 4;
    int r0 = (blockIdx.x * 4 + wave) * 16;   // 625*4*16 = 40000 exact

    f32x4 acc[8];
#pragma unroll
    for (int t = 0; t < 8; ++t) acc[t] = (f32x4){0.f, 0.f, 0.f, 0.f};

    float asv[8], adv[8];
#pragma unroll
    for (int t = 0; t < 8; ++t) {
        int c = t * 16 + l15;
        asv[t] = asrc[c];
        adv[t] = adst[c];
    }

    const unsigned short* xrow = Xb + (long)(r0 + l15) * 128 + q * 8;
    const unsigned short* wrow = Wt + (long)l15 * 128 + q * 8;
#pragma unroll
    for (int kt = 0; kt < 4; ++kt) {
        bf16x8 a = *(const bf16x8*)(xrow + kt * 32);
#pragma unroll
        for (int t = 0; t < 8; ++t) {
            bf16x8 b = *(const bf16x8*)(wrow + (long)t * 16 * 128 + kt * 32);
            acc[t] = __builtin_amdgcn_mfma_f32_16x16x32_bf16(a, b, acc[t], 0, 0, 0);
        }
    }

#pragma unroll
    for (int t = 0; t < 8; ++t)
#pragma unroll
        for (int i = 0; i < 4; ++i)
            Hb[(long)(r0 + q * 4 + i) * 128 + t * 16 + l15] = f2bf(acc[t][i]);

#pragma unroll
    for (int i = 0; i < 4; ++i) {
        float ps0 = acc[0][i] * asv[0] + acc[1][i] * asv[1];
        float ps1 = acc[2][i] * asv[2] + acc[3][i] * asv[3];
        float ps2 = acc[4][i] * asv[4] + acc[5][i] * asv[5];
        float ps3 = acc[6][i] * asv[6] + acc[7][i] * asv[7];
        float pd0 = acc[0][i] * adv[0] + acc[1][i] * adv[1];
        float pd1 = acc[2][i] * adv[2] + acc[3][i] * adv[3];
        float pd2 = acc[4][i] * adv[4] + acc[5][i] * adv[5];
        float pd3 = acc[6][i] * adv[6] + acc[7][i] * adv[7];
#pragma unroll
        for (int m = 1; m < 16; m <<= 1) {
            ps0 += __shfl_xor(ps0, m, 16); ps1 += __shfl_xor(ps1, m, 16);
            ps2 += __shfl_xor(ps2, m, 16); ps3 += __shfl_xor(ps3, m, 16);
            pd0 += __shfl_xor(pd0, m, 16); pd1 += __shfl_xor(pd1, m, 16);
            pd2 += __shfl_xor(pd2, m, 16); pd3 += __shfl_xor(pd3, m, 16);
        }
        int r = r0 + q * 4 + i;
        if (l15 < 4) {
            float v = (l15 == 0) ? ps0 : (l15 == 1) ? ps1 : (l15 == 2) ? ps2 : ps3;
            ALS_t[l15 * N_NODES + r] = v;
        } else if (l15 < 8) {
            int h = l15 - 4;
            float v = (h == 0) ? pd0 : (h == 1) ? pd1 : (h == 2) ? pd2 : pd3;
            ALD_t[h * N_NODES + r] = v;
        }
    }
}

// ---------------- MFMA GEMM (128 -> 32, 1 head) ----------------
__global__ __launch_bounds__(256) void gemm32_mfma(const unsigned short* __restrict__ Xb,
                                                   const unsigned short* __restrict__ Wt2,
                                                   const float* __restrict__ asrc,
                                                   const float* __restrict__ adst,
                                                   unsigned short* __restrict__ H2b,
                                                   float* __restrict__ ALS,
                                                   float* __restrict__ ALD) {
    int wave = threadIdx.x >> 6;
    int lane = threadIdx.x & 63;
    int l15 = lane & 15;
    int q = lane >> 4;
    int r0 = (blockIdx.x * 4 + wave) * 16;   // 625*4*16 = 40000 exact

    f32x4 acc[2];
    acc[0] = (f32x4){0.f, 0.f, 0.f, 0.f};
    acc[1] = (f32x4){0.f, 0.f, 0.f, 0.f};

    const unsigned short* xrow = Xb + (long)(r0 + l15) * 128 + q * 8;
    const unsigned short* wrow = Wt2 + (long)l15 * 128 + q * 8;
#pragma unroll
    for (int kt = 0; kt < 4; ++kt) {
        bf16x8 a = *(const bf16x8*)(xrow + kt * 32);
#pragma unroll
        for (int t = 0; t < 2; ++t) {
            bf16x8 b = *(const bf16x8*)(wrow + (long)t * 16 * 128 + kt * 32);
            acc[t] = __builtin_amdgcn_mfma_f32_16x16x32_bf16(a, b, acc[t], 0, 0, 0);
        }
    }

    float as0 = asrc[l15], as1 = asrc[16 + l15];
    float ad0 = adst[l15], ad1 = adst[16 + l15];
#pragma unroll
    for (int t = 0; t < 2; ++t)
#pragma unroll
        for (int i = 0; i < 4; ++i)
            H2b[(long)(r0 + q * 4 + i) * 32 + t * 16 + l15] = f2bf(acc[t][i]);

#pragma unroll
    for (int i = 0; i < 4; ++i) {
        float ps = acc[0][i] * as0 + acc[1][i] * as1;
        float pd = acc[0][i] * ad0 + acc[1][i] * ad1;
#pragma unroll
        for (int m = 1; m < 16; m <<= 1) {
            ps += __shfl_xor(ps, m, 16);
            pd += __shfl_xor(pd, m, 16);
        }
        if (l15 == 0) {
            int r = r0 + q * 4 + i;
            ALS[r] = ps;
            ALD[r] = pd;
        }
    }
}

// ---------------- Edge aggregation, CSR by dst, batched-gather ----------------
// Transposed logits: lane's ALS gather is a distinct needed 4B (no float4 waste,
// no quad redundancy).
__global__ __launch_bounds__(256) void agg128(const unsigned short* __restrict__ Hb,
                                              const float* __restrict__ ALS_t,
                                              const float* __restrict__ ALD_t,
                                              const int* __restrict__ offs,
                                              const int* __restrict__ ssrc,
                                              const float* __restrict__ bias,
                                              unsigned short* __restrict__ OUTb) {
    int n = blockIdx.x * 4 + (threadIdx.x >> 6);
    n = __builtin_amdgcn_readfirstlane(n);
    if (n >= N_NODES) return;
    int lane = threadIdx.x & 63;
    int c = lane * 2;
    int head = lane >> 4;
    int e16 = lane & 15;
    float aldh = ALD_t[head * N_NODES + n];
    const float* alsh = ALS_t + (long)head * N_NODES;
    int j0 = __builtin_amdgcn_readfirstlane(offs[n]);
    int j1 = __builtin_amdgcn_readfirstlane(offs[n + 1]);
    float a0 = 0.f, a1 = 0.f, dsum = 0.f;
    for (int jb = j0; jb < j1; jb += 16) {
        int j = jb + e16;
        int jc = (j < j1) ? j : (j1 - 1);
        int s = ssrc[jc];
        float e = alsh[s] + aldh;
        e = (e > 0.f) ? e : 0.2f * e;
        float w = (j < j1) ? __expf(e) : 0.f;
        int st[16]; float wt[16];
#pragma unroll
        for (int t = 0; t < 16; ++t) {
            st[t] = __shfl(s, t, 16);
            wt[t] = __shfl(w, t, 16);
        }
        unsigned int hv[16];
#pragma unroll
        for (int t = 0; t < 16; ++t)
            hv[t] = *(const unsigned int*)(Hb + (long)st[t] * 128 + c);
#pragma unroll
        for (int t = 0; t < 16; ++t) {
            float h0 = bf2f((unsigned short)(hv[t] & 0xFFFF));
            float h1 = bf2f((unsigned short)(hv[t] >> 16));
            dsum += wt[t];
            a0 += wt[t] * h0;
            a1 += wt[t] * h1;
        }
    }
    float inv = 1.0f / dsum;
    float o0 = a0 * inv + bias[c];
    float o1 = a1 * inv + bias[c + 1];
    o0 = (o0 > 0.f) ? o0 : (__expf(o0) - 1.f);
    o1 = (o1 > 0.f) ? o1 : (__expf(o1) - 1.f);
    ushort2 ob; ob.x = f2bf(o0); ob.y = f2bf(o1);
    *(ushort2*)(OUTb + (long)n * 128 + c) = ob;
}

__global__ __launch_bounds__(256) void agg32(const unsigned short* __restrict__ H2b,
                                             const float* __restrict__ ALS,
                                             const float* __restrict__ ALD,
                                             const int* __restrict__ offs,
                                             const int* __restrict__ ssrc,
                                             const float* __restrict__ bias,
                                             float* __restrict__ OUT) {
    int wv = blockIdx.x * 4 + (threadIdx.x >> 6);
    int lane = threadIdx.x & 63;
    int col = lane & 31;
    int half = lane >> 5;
    int e16 = lane & 15;
    int n = wv * 2 + half;
    if (n >= N_NODES) return;
    float aldn = ALD[n];
    int j0 = offs[n], j1 = offs[n + 1];
    float a = 0.f, dsum = 0.f;
    for (int jb = j0; jb < j1; jb += 16) {
        int j = jb + e16;
        int jc = (j < j1) ? j : (j1 - 1);
        int s = ssrc[jc];
        float e = ALS[s] + aldn;
        e = (e > 0.f) ? e : 0.2f * e;
        float w = (j < j1) ? __expf(e) : 0.f;
        int st[16]; float wt[16];
#pragma unroll
        for (int t = 0; t < 16; ++t) {
            st[t] = __shfl(s, t, 16);
            wt[t] = __shfl(w, t, 16);
        }
        unsigned short hv[16];
#pragma unroll
        for (int t = 0; t < 16; ++t)
            hv[t] = H2b[st[t] * 32 + col];
#pragma unroll
        for (int t = 0; t < 16; ++t) {
            dsum += wt[t];
            a += wt[t] * bf2f(hv[t]);
        }
    }
    float o = a / dsum + bias[col];
    o = (o > 0.f) ? o : (__expf(o) - 1.f);
    OUT[n * 32 + col] = o;
}

// ---------------- Pooling + MLP ----------------
__global__ __launch_bounds__(256) void pool_kernel(const float* __restrict__ H3,
                                                   const int* __restrict__ batch,
                                                   float* __restrict__ gsum,
                                                   float* __restrict__ gcnt) {
    const int CHUNK = 40;
    int gid = (blockIdx.x * 256 + threadIdx.x) >> 5;
    int c = threadIdx.x & 31;
    int n0 = gid * CHUNK;
    if (n0 >= N_NODES) return;
    int n1 = n0 + CHUNK;
    if (n1 > N_NODES) n1 = N_NODES;
    int cur = batch[n0];
    float acc = 0.f;
    int cnt = 0;
    for (int n = n0; n < n1; ++n) {
        int b = batch[n];
        if (b != cur) {
            atomicAdd(&gsum[cur * 32 + c], acc);
            if (c == 0) atomicAdd(&gcnt[cur], (float)cnt);
            cur = b; acc = 0.f; cnt = 0;
        }
        acc += H3[n * 32 + c];
        cnt++;
    }
    atomicAdd(&gsum[cur * 32 + c], acc);
    if (c == 0) atomicAdd(&gcnt[cur], (float)cnt);
}

__global__ __launch_bounds__(256) void mlp_kernel(const float* __restrict__ gsum,
                                                  const float* __restrict__ gcnt,
                                                  const float* __restrict__ l1w,
                                                  const float* __restrict__ l1b,
                                                  const float* __restrict__ l2w,
                                                  const float* __restrict__ l2b,
                                                  float* __restrict__ out) {
    __shared__ float g[NUM_GRAPHS * 32];
    __shared__ float t1[NUM_GRAPHS * 128];
    int tid = threadIdx.x;
    for (int i = tid; i < NUM_GRAPHS * 32; i += 256) {
        float c = gcnt[i >> 5];
        g[i] = gsum[i] / fmaxf(c, 1.0f);
    }
    __syncthreads();
    for (int i = tid; i < NUM_GRAPHS * 128; i += 256) {
        int r = i >> 7, j = i & 127;
        float a = l1b[j];
        for (int k = 0; k < 32; ++k) a += g[r * 32 + k] * l1w[k * 128 + j];
        t1[i] = fmaxf(a, 0.f);
    }
    __syncthreads();
    for (int i = tid; i < NUM_GRAPHS * 8; i += 256) {
        int r = i >> 3, j = i & 7;
        float a = l2b[j];
        for (int k = 0; k < 128; ++k) a += t1[r * 128 + k] * l2w[k * 8 + j];
        out[i] = a;
    }
}

// ---------------- host ----------------

extern "C" void kernel_launch(void* const* d_in, const int* in_sizes, int n_in,
                              void* d_out, int out_size, void* d_ws, size_t ws_size,
                              hipStream_t stream) {
    const float* x      = (const float*)d_in[0];
    const int*   eidx   = (const int*)d_in[1];
    const int*   batch  = (const int*)d_in[2];
    const float* W0     = (const float*)d_in[3];
    const float* asrc0  = (const float*)d_in[4];
    const float* adst0  = (const float*)d_in[5];
    const float* b0     = (const float*)d_in[6];
    const float* W1     = (const float*)d_in[7];
    const float* asrc1  = (const float*)d_in[8];
    const float* adst1  = (const float*)d_in[9];
    const float* b1     = (const float*)d_in[10];
    const float* W2     = (const float*)d_in[11];
    const float* asrc2  = (const float*)d_in[12];
    const float* adst2  = (const float*)d_in[13];
    const float* b2     = (const float*)d_in[14];
    const float* l1w    = (const float*)d_in[15];
    const float* l1b    = (const float*)d_in[16];
    const float* l2w    = (const float*)d_in[17];
    const float* l2b    = (const float*)d_in[18];
    float* out = (float*)d_out;

    const int* esrc = eidx;
    const int* edst = eidx + N_EDGES;

    // workspace layout
    float* ALS  = (float*)d_ws;                       // N*4 (transposed [4][N]; layer2 uses [N])
    float* ALD  = ALS + N_NODES * 4;                  // N*4 (transposed [4][N]; layer2 uses [N])
    float* h3   = ALD + N_NODES * 4;                  // N*32
    int* counts = (int*)(h3 + (long)N_NODES * 32);    // N      <- zero from here
    float* gsum = (float*)(counts + N_NODES);         // 64*32
    float* gcnt = gsum + NUM_GRAPHS * 32;             // 64     <- zero to here
    int* offs   = (int*)(gcnt + NUM_GRAPHS);          // N+1
    int* bsum   = offs + (N_NODES + 1);               // SCAN_BLOCKS
    int* bofs   = bsum + SCAN_BLOCKS;                 // SCAN_BLOCKS
    int* rank   = bofs + SCAN_BLOCKS;                 // E_TOT
    int* ssrc   = rank + E_TOT;                       // E_TOT
    // align bf16 region to 16B
    uintptr_t p = (uintptr_t)(ssrc + E_TOT);
    p = (p + 15) & ~(uintptr_t)15;
    unsigned short* Xb   = (unsigned short*)p;              // N*128 bf16
    unsigned short* Hb   = Xb + (long)N_NODES * 128;        // N*128 bf16
    unsigned short* OUTb = Hb + (long)N_NODES * 128;        // N*128 bf16
    unsigned short* H2b  = OUTb + (long)N_NODES * 128;      // N*32 bf16
    unsigned short* Wt0  = H2b + (long)N_NODES * 32;        // 128*128 bf16
    unsigned short* Wt1  = Wt0 + 128 * 128;                 // 128*128 bf16
    unsigned short* Wt2  = Wt1 + 128 * 128;                 // 32*128 bf16

    // fused setup: cvt_x + cvt_w + zero(counts/gsum/gcnt)
    setup_kernel<<<CVTX_BLOCKS + CVTW_BLOCKS + ZERO_BLOCKS, 256, 0, stream>>>(
        x, W0, W1, W2, Xb, Wt0, Wt1, Wt2, counts);

    // CSR build
    int eblocks = (E_TOT + 255) / 256;
    hist_rank_kernel<<<eblocks, 256, 0, stream>>>(edst, counts, rank);
    bsum_kernel<<<SCAN_BLOCKS, 256, 0, stream>>>(counts, bsum);
    bscan_kernel<<<1, 256, 0, stream>>>(bsum, bofs);
    boffs_kernel<<<SCAN_BLOCKS, 256, 0, stream>>>(counts, bofs, offs);
    scatter_kernel<<<eblocks, 256, 0, stream>>>(esrc, edst, offs, rank, ssrc);

    // layer 0
    gemm128_mfma<<<625, 256, 0, stream>>>(Xb, Wt0, asrc0, adst0, Hb, ALS, ALD);
    agg128<<<10000, 256, 0, stream>>>(Hb, ALS, ALD, offs, ssrc, b0, OUTb);

    // layer 1
    gemm128_mfma<<<625, 256, 0, stream>>>(OUTb, Wt1, asrc1, adst1, Hb, ALS, ALD);
    agg128<<<10000, 256, 0, stream>>>(Hb, ALS, ALD, offs, ssrc, b1, OUTb);

    // layer 2
    gemm32_mfma<<<625, 256, 0, stream>>>(OUTb, Wt2, asrc2, adst2, H2b, ALS, ALD);
    agg32<<<5000, 256, 0, stream>>>(H2b, ALS, ALD, offs, ssrc, b2, h3);

    // pool + MLP
    pool_kernel<<<125, 256, 0, stream>>>(h3, batch, gsum, gcnt);
    mlp_kernel<<<1, 256, 0, stream>>>(gsum, gcnt, l1w, l1b, l2w, l2b, out);
}